// Round 11
// baseline (571.253 us; speedup 1.0000x reference)
//
#include <hip/hip_runtime.h>

typedef unsigned short ushort_t;
typedef __attribute__((ext_vector_type(8))) __bf16 bf16x8;
typedef __attribute__((ext_vector_type(8))) unsigned short ushort8v;
typedef __attribute__((ext_vector_type(4))) float floatx4;

__device__ inline float b2f(ushort_t u) {
    union { unsigned int i; float f; } c; c.i = ((unsigned int)u) << 16; return c.f;
}
__device__ inline ushort_t f2b(float f) {
    union { float f; unsigned int i; } c; c.f = f;
    unsigned int i = c.i;
    unsigned int r = (i + 0x7FFFu + ((i >> 16) & 1u)) >> 16;
    return (ushort_t)r;
}
__device__ inline bf16x8 as_bf16x8(ushort8v u) { return __builtin_bit_cast(bf16x8, u); }

// Async global->LDS, 16 B per lane (m97). LDS dest = wave-uniform base +
// lane*16; LDS layout must be contiguous in lane order.
__device__ inline void load_lds16(const ushort_t* g, ushort_t* l) {
    __builtin_amdgcn_global_load_lds(
        (const __attribute__((address_space(1))) void*)g,
        (__attribute__((address_space(3))) void*)l, 16, 0, 0);
}

// ---------------------------------------------------------------------------
// bias concat: o[0..3072) = bq | bk | bv
// ---------------------------------------------------------------------------
__global__ __launch_bounds__(256) void concat3_kernel(
    const float* __restrict__ a, const float* __restrict__ b,
    const float* __restrict__ c, float* __restrict__ o) {
    int t = blockIdx.x * 256 + threadIdx.x;
    if (t < 3072)
        o[t] = t < 1024 ? a[t] : (t < 2048 ? b[t - 1024] : c[t - 2048]);
}

// ---------------------------------------------------------------------------
// fp32 copy (x -> outf), float4 vectorized.
// ---------------------------------------------------------------------------
__global__ __launch_bounds__(256) void copy_f32_kernel(
    const float* __restrict__ src, float* __restrict__ dst) {
    size_t i = ((size_t)blockIdx.x * 256 + threadIdx.x) * 4;
    *(float4*)(dst + i) = *(const float4*)(src + i);
}

// ---------------------------------------------------------------------------
// ALL weight transposes in one dispatch. 12288 32x32 tiles, 1-D grid:
//   [0,1024)Wq [1024,2048)Wk [2048,3072)Wv [3072,4096)Wo
//   [4096,8192)W1 (128x32 tiles)  [8192,12288)W2 (32x128 tiles)
// out[c*R + r] = bf16(in[r*ld + c]).
// ---------------------------------------------------------------------------
__global__ __launch_bounds__(256) void transpose_all_kernel(
    const float* __restrict__ Wq, const float* __restrict__ Wk,
    const float* __restrict__ Wv, const float* __restrict__ Wo,
    const float* __restrict__ W1, const float* __restrict__ W2,
    ushort_t* __restrict__ dq, ushort_t* __restrict__ dk,
    ushort_t* __restrict__ dv, ushort_t* __restrict__ do_,
    ushort_t* __restrict__ d1, ushort_t* __restrict__ d2) {
    int t = blockIdx.x;
    const float* src; ushort_t* dst; int R, ld, tcx, tcy;
    if (t < 4096) {
        int id = t >> 10, u = t & 1023;
        tcx = u & 31; tcy = u >> 5; R = 1024; ld = 1024;
        src = id == 0 ? Wq : id == 1 ? Wk : id == 2 ? Wv : Wo;
        dst = id == 0 ? dq : id == 1 ? dk : id == 2 ? dv : do_;
    } else if (t < 8192) {
        int u = t - 4096;
        tcx = u & 127; tcy = u >> 7; R = 1024; ld = 4096;
        src = W1; dst = d1;
    } else {
        int u = t - 8192;
        tcx = u & 31; tcy = u >> 5; R = 4096; ld = 1024;
        src = W2; dst = d2;
    }
    __shared__ float tile[32][33];
    int tx = threadIdx.x, ty = threadIdx.y;
    int r0 = tcy * 32, c0 = tcx * 32;
#pragma unroll
    for (int i = 0; i < 32; i += 8)
        tile[ty + i][tx] = src[(size_t)(r0 + ty + i) * ld + c0 + tx];
    __syncthreads();
#pragma unroll
    for (int i = 0; i < 32; i += 8)
        dst[(size_t)(c0 + ty + i) * R + r0 + tx] = f2b(tile[tx][ty + i]);
}

// ---------------------------------------------------------------------------
// Per-head V transpose (bf16): qkv [B*S][3072] (V at col 2048+h*64) ->
// vt [bh][64][2048].  grid (S/32, 2, 32), block (32,8).
// ---------------------------------------------------------------------------
__global__ __launch_bounds__(256) void transpose_v_kernel(
    const ushort_t* __restrict__ qkv, ushort_t* __restrict__ vt) {
    __shared__ ushort_t tile[32][33];
    int tx = threadIdx.x, ty = threadIdx.y;
    int s0 = blockIdx.x * 32, d0 = blockIdx.y * 32;
    int bh = blockIdx.z, b = bh >> 4, h = bh & 15;
    const ushort_t* src = qkv + (size_t)b * 2048 * 3072 + 2048 + h * 64;
    ushort_t* dst = vt + (size_t)bh * 64 * 2048;
#pragma unroll
    for (int i = 0; i < 32; i += 8)
        tile[ty + i][tx] = src[(size_t)(s0 + ty + i) * 3072 + d0 + tx];
    __syncthreads();
#pragma unroll
    for (int i = 0; i < 32; i += 8)
        dst[(size_t)(d0 + ty + i) * 2048 + s0 + tx] = tile[tx][ty + i];
}

// ---------------------------------------------------------------------------
// LayerNorm: rows of 1024, fp32 in -> bf16 out.
// ---------------------------------------------------------------------------
__device__ inline float wave_sum(float s) {
#pragma unroll
    for (int o = 32; o > 0; o >>= 1) s += __shfl_xor(s, o);
    return s;
}

__global__ __launch_bounds__(256) void ln_f32_kernel(
    const float* __restrict__ x, const float* __restrict__ sc,
    const float* __restrict__ bi, ushort_t* __restrict__ out) {
    int row = blockIdx.x, t = threadIdx.x;
    const float* xr = x + (size_t)row * 1024;
    float4 u = *(const float4*)(xr + t * 4);
    float v0 = u.x, v1 = u.y, v2 = u.z, v3 = u.w;
    __shared__ float sm[8];
    int wv = t >> 6, lane = t & 63;
    float s = wave_sum(v0 + v1 + v2 + v3);
    if (lane == 0) sm[wv] = s;
    __syncthreads();
    float mean = (sm[0] + sm[1] + sm[2] + sm[3]) * (1.0f / 1024.0f);
    float d0 = v0 - mean, d1 = v1 - mean, d2 = v2 - mean, d3 = v3 - mean;
    float q = wave_sum(d0 * d0 + d1 * d1 + d2 * d2 + d3 * d3);
    if (lane == 0) sm[4 + wv] = q;
    __syncthreads();
    float var = (sm[4] + sm[5] + sm[6] + sm[7]) * (1.0f / 1024.0f);
    float rn = rsqrtf(var + 1e-6f);
    float4 us = *(const float4*)(sc + t * 4);
    float4 ub = *(const float4*)(bi + t * 4);
    ushort4 o;
    o.x = f2b(d0 * rn * us.x + ub.x);
    o.y = f2b(d1 * rn * us.y + ub.y);
    o.z = f2b(d2 * rn * us.z + ub.z);
    o.w = f2b(d3 * rn * us.w + ub.w);
    *(ushort4*)(out + (size_t)row * 1024 + t * 4) = o;
}

// ---------------------------------------------------------------------------
// GEMM: acc[M][N] = A[M][K] @ Bt[N][K]^T (bf16 in, fp32 acc).
// 128x128 tile, BK=64, global_load_lds staging, unpadded [128][64] LDS.
// op: 0: Cb=bf16(acc+bias)  1: Cb=bf16(relu(acc+bias))
//     2: Cf=acc+bias+resf   3: Cf=acc+resf      (resf may alias Cf)
// ---------------------------------------------------------------------------
__global__ __launch_bounds__(256) void gemm_bt_kernel(
    const ushort_t* __restrict__ A, const ushort_t* __restrict__ Bt,
    const float* __restrict__ bias, const float* __restrict__ resf,
    ushort_t* __restrict__ Cb, float* __restrict__ Cf,
    int M, int N, int K, int ldb, int op) {
    __shared__ __align__(16) ushort_t As[128 * 64];
    __shared__ __align__(16) ushort_t Bs[128 * 64];
    int tid = threadIdx.x;
    int m0 = blockIdx.y * 128, n0 = blockIdx.x * 128;
    int wv = tid >> 6, lane = tid & 63;
    int wr = wv & 1, wc = wv >> 1;
    int mo = wr * 64, no = wc * 64;
    int quad = lane >> 4, l16 = lane & 15;
    int k8 = quad * 8;

    floatx4 acc[4][4] = {};

    for (int k0 = 0; k0 < K; k0 += 64) {
#pragma unroll
        for (int c = 0; c < 4; ++c) {
            int e = c * 2048 + tid * 8;
            int r = e >> 6, kk = e & 63;
            int wbase = c * 2048 + wv * 512;
            load_lds16(A + (size_t)(m0 + r) * K + k0 + kk, As + wbase);
            load_lds16(Bt + (size_t)(n0 + r) * ldb + k0 + kk, Bs + wbase);
        }
        __syncthreads();
#pragma unroll
        for (int h = 0; h < 2; ++h) {
            bf16x8 af[4], bfr[4];
#pragma unroll
            for (int i = 0; i < 4; ++i) {
                af[i]  = as_bf16x8(*(const ushort8v*)(As + (mo + i * 16 + l16) * 64 + h * 32 + k8));
                bfr[i] = as_bf16x8(*(const ushort8v*)(Bs + (no + i * 16 + l16) * 64 + h * 32 + k8));
            }
#pragma unroll
            for (int mi = 0; mi < 4; ++mi)
#pragma unroll
                for (int ni = 0; ni < 4; ++ni)
                    acc[mi][ni] = __builtin_amdgcn_mfma_f32_16x16x32_bf16(
                        af[mi], bfr[ni], acc[mi][ni], 0, 0, 0);
        }
        __syncthreads();
    }

#pragma unroll
    for (int mi = 0; mi < 4; ++mi) {
#pragma unroll
        for (int r = 0; r < 4; ++r) {
            int row = m0 + mo + mi * 16 + quad * 4 + r;
            size_t rowoff = (size_t)row * N;
#pragma unroll
            for (int ni = 0; ni < 4; ++ni) {
                int col = n0 + no + ni * 16 + l16;
                float val = acc[mi][ni][r];
                if (op != 3) val += bias[col];
                if (op == 1) val = fmaxf(val, 0.0f);
                if (op >= 2) {
                    val += resf[rowoff + col];
                    Cf[rowoff + col] = val;
                } else {
                    Cb[rowoff + col] = f2b(val);
                }
            }
        }
    }
}

// ---------------------------------------------------------------------------
// Split-K GEMM, atomic fp32 epilogue: Cf[m][n] += acc_z (+bias if z==0).
// Cf pre-initialized with the residual term.
// ---------------------------------------------------------------------------
__global__ __launch_bounds__(256) void gemm_bt_atomic_kernel(
    const ushort_t* __restrict__ A, const ushort_t* __restrict__ Bt,
    const float* __restrict__ bias, float* __restrict__ Cf,
    int M, int N, int lda, int ldb, int Kc) {
    __shared__ __align__(16) ushort_t As[128 * 64];
    __shared__ __align__(16) ushort_t Bs[128 * 64];
    int tid = threadIdx.x;
    int m0 = blockIdx.y * 128, n0 = blockIdx.x * 128;
    int kbase = blockIdx.z * Kc;
    int wv = tid >> 6, lane = tid & 63;
    int wr = wv & 1, wc = wv >> 1;
    int mo = wr * 64, no = wc * 64;
    int quad = lane >> 4, l16 = lane & 15;
    int k8 = quad * 8;

    floatx4 acc[4][4] = {};

    for (int k0 = kbase; k0 < kbase + Kc; k0 += 64) {
#pragma unroll
        for (int c = 0; c < 4; ++c) {
            int e = c * 2048 + tid * 8;
            int r = e >> 6, kk = e & 63;
            int wbase = c * 2048 + wv * 512;
            load_lds16(A + (size_t)(m0 + r) * lda + k0 + kk, As + wbase);
            load_lds16(Bt + (size_t)(n0 + r) * ldb + k0 + kk, Bs + wbase);
        }
        __syncthreads();
#pragma unroll
        for (int h = 0; h < 2; ++h) {
            bf16x8 af[4], bfr[4];
#pragma unroll
            for (int i = 0; i < 4; ++i) {
                af[i]  = as_bf16x8(*(const ushort8v*)(As + (mo + i * 16 + l16) * 64 + h * 32 + k8));
                bfr[i] = as_bf16x8(*(const ushort8v*)(Bs + (no + i * 16 + l16) * 64 + h * 32 + k8));
            }
#pragma unroll
            for (int mi = 0; mi < 4; ++mi)
#pragma unroll
                for (int ni = 0; ni < 4; ++ni)
                    acc[mi][ni] = __builtin_amdgcn_mfma_f32_16x16x32_bf16(
                        af[mi], bfr[ni], acc[mi][ni], 0, 0, 0);
        }
        __syncthreads();
    }

    bool addb = (blockIdx.z == 0) && (bias != nullptr);
#pragma unroll
    for (int mi = 0; mi < 4; ++mi) {
#pragma unroll
        for (int r = 0; r < 4; ++r) {
            int row = m0 + mo + mi * 16 + quad * 4 + r;
            size_t rowoff = (size_t)row * N;
#pragma unroll
            for (int ni = 0; ni < 4; ++ni) {
                int col = n0 + no + ni * 16 + l16;
                float val = acc[mi][ni][r];
                if (addb) val += bias[col];
                unsafeAtomicAdd(&Cf[rowoff + col], val);
            }
        }
    }
}

// ---------------------------------------------------------------------------
// Flash attention, BARRIER-FREE: K/V MFMA fragments loaded directly
// global->register (no LDS staging, no __syncthreads anywhere; cross-wave
// sharing traded for wave decoupling - K/V served from L2, 16 blocks/head).
// Ps (P layout round-trip) is per-wave LDS: same-wave write->read, no sync.
// Shuffle-free softmax (scores ~N(0,1)); row-sum via MFMA with ones.
// BQ=128 (2 m-tiles/wave). grid (S/128, B*H).
// ---------------------------------------------------------------------------
__global__ __launch_bounds__(256) void attn_kernel(
    const ushort_t* __restrict__ qkv, const ushort_t* __restrict__ vt,
    ushort_t* __restrict__ om) {
    const int LDQ = 3072, LDO = 1024;
    int bh = blockIdx.y;
    int b = bh >> 4, h = bh & 15;
    size_t qbase = (size_t)b * 2048 * LDQ + h * 64;
    const ushort_t* kp = qkv + qbase + 1024;
    const ushort_t* vtp = vt + (size_t)bh * 64 * 2048;
    int q0 = blockIdx.x * 128;
    int tid = threadIdx.x, wv = tid >> 6, lane = tid & 63;
    int quad = lane >> 4, l16 = lane & 15;
    int k8 = quad * 8;

    __shared__ __align__(16) ushort_t Ps[4 * 32 * 76];
    ushort_t* ps = Ps + wv * 32 * 76;

    bf16x8 qf[2][2];
#pragma unroll
    for (int mt = 0; mt < 2; ++mt) {
        const ushort_t* qptr = qkv + qbase + (size_t)(q0 + wv * 32 + mt * 16 + l16) * LDQ;
        qf[mt][0] = as_bf16x8(*(const ushort8v*)(qptr + k8));
        qf[mt][1] = as_bf16x8(*(const ushort8v*)(qptr + 32 + k8));
    }

    bf16x8 ones;
#pragma unroll
    for (int j = 0; j < 8; ++j) ones[j] = (__bf16)1.0f;

    floatx4 Oacc[2][4] = {};
    floatx4 lsum[2] = {};

    for (int kb = 0; kb < 2048; kb += 64) {
        // K fragments straight from global (B-layout: row kb+kt*16+l16)
        bf16x8 kf[4][2];
#pragma unroll
        for (int kt = 0; kt < 4; ++kt) {
            const ushort_t* kr = kp + (size_t)(kb + kt * 16 + l16) * LDQ + k8;
            kf[kt][0] = as_bf16x8(*(const ushort8v*)(kr));
            kf[kt][1] = as_bf16x8(*(const ushort8v*)(kr + 32));
        }

        floatx4 sc[2][4];
#pragma unroll
        for (int mt = 0; mt < 2; ++mt)
#pragma unroll
            for (int kt = 0; kt < 4; ++kt) {
                floatx4 s = {0.0f, 0.0f, 0.0f, 0.0f};
                s = __builtin_amdgcn_mfma_f32_16x16x32_bf16(qf[mt][0], kf[kt][0], s, 0, 0, 0);
                s = __builtin_amdgcn_mfma_f32_16x16x32_bf16(qf[mt][1], kf[kt][1], s, 0, 0, 0);
                sc[mt][kt] = s;
            }

        // P = exp(s/8) -> per-wave LDS (C-layout write), native bf16 cvt
#pragma unroll
        for (int mt = 0; mt < 2; ++mt)
#pragma unroll
            for (int kt = 0; kt < 4; ++kt)
#pragma unroll
                for (int r = 0; r < 4; ++r) {
                    __bf16 pb = (__bf16)__expf(sc[mt][kt][r] * 0.125f);
                    ps[(mt * 16 + quad * 4 + r) * 76 + kt * 16 + l16] =
                        __builtin_bit_cast(ushort_t, pb);
                }

        // V fragments straight from global (vt row dt*16+l16, cols kb..)
        bf16x8 vf[4][2];
#pragma unroll
        for (int dt = 0; dt < 4; ++dt) {
            const ushort_t* vr = vtp + (size_t)(dt * 16 + l16) * 2048 + kb + k8;
            vf[dt][0] = as_bf16x8(*(const ushort8v*)(vr));
            vf[dt][1] = as_bf16x8(*(const ushort8v*)(vr + 32));
        }

#pragma unroll
        for (int mt = 0; mt < 2; ++mt) {
            bf16x8 pf0 = as_bf16x8(*(const ushort8v*)(ps + (mt * 16 + l16) * 76 + k8));
            bf16x8 pf1 = as_bf16x8(*(const ushort8v*)(ps + (mt * 16 + l16) * 76 + 32 + k8));
#pragma unroll
            for (int dt = 0; dt < 4; ++dt) {
                Oacc[mt][dt] = __builtin_amdgcn_mfma_f32_16x16x32_bf16(pf0, vf[dt][0], Oacc[mt][dt], 0, 0, 0);
                Oacc[mt][dt] = __builtin_amdgcn_mfma_f32_16x16x32_bf16(pf1, vf[dt][1], Oacc[mt][dt], 0, 0, 0);
            }
            lsum[mt] = __builtin_amdgcn_mfma_f32_16x16x32_bf16(pf0, ones, lsum[mt], 0, 0, 0);
            lsum[mt] = __builtin_amdgcn_mfma_f32_16x16x32_bf16(pf1, ones, lsum[mt], 0, 0, 0);
        }
    }

#pragma unroll
    for (int mt = 0; mt < 2; ++mt)
#pragma unroll
        for (int r = 0; r < 4; ++r) {
            float inv = 1.0f / lsum[mt][r];
            size_t rowoff = (size_t)(b * 2048 + q0 + wv * 32 + mt * 16 + quad * 4 + r) * LDO + h * 64;
#pragma unroll
            for (int dt = 0; dt < 4; ++dt)
                om[rowoff + dt * 16 + l16] = f2b(Oacc[mt][dt][r] * inv);
        }
}

// ---------------------------------------------------------------------------
// Workspace map (bf16 elems, M1 = 1048576), peak 28M elems = 56 MB (proven):
//   qkvT [0,3M)  WoT [3M,4M)  W1T [4M,8M)  W2T [8M,12M)
//   h/attnout [12M,16M)   qkv [16M,28M)
//   h2 -> [0,4M) after qkvT/WoT die; ffbuf -> [12M,28M) after attnout/qkv die
// d_out timeline: bqkv (12 KB) -> vt (8 MB bf16) -> outf (x2 fp32 16 MB).
// ---------------------------------------------------------------------------
extern "C" void kernel_launch(void* const* d_in, const int* in_sizes, int n_in,
                              void* d_out, int out_size, void* d_ws, size_t ws_size,
                              hipStream_t stream) {
    const float* x    = (const float*)d_in[0];
    const float* Wq   = (const float*)d_in[1];
    const float* bq   = (const float*)d_in[2];
    const float* Wk   = (const float*)d_in[3];
    const float* bk   = (const float*)d_in[4];
    const float* Wv   = (const float*)d_in[5];
    const float* bv   = (const float*)d_in[6];
    const float* Wo   = (const float*)d_in[7];
    const float* bo   = (const float*)d_in[8];
    const float* W1   = (const float*)d_in[9];
    const float* b1   = (const float*)d_in[10];
    const float* W2   = (const float*)d_in[11];
    const float* b2   = (const float*)d_in[12];
    const float* ln1s = (const float*)d_in[13];
    const float* ln1b = (const float*)d_in[14];
    const float* ln2s = (const float*)d_in[15];
    const float* ln2b = (const float*)d_in[16];
    float*    outf = (float*)d_out;
    ushort_t* ws   = (ushort_t*)d_ws;

    const size_t M1 = 1048576;
    ushort_t* qkvT    = ws;
    ushort_t* WoT     = ws + 3 * M1;
    ushort_t* W1T     = ws + 4 * M1;
    ushort_t* W2T     = ws + 8 * M1;
    ushort_t* h       = ws + 12 * M1;
    ushort_t* attnout = ws + 12 * M1;
    ushort_t* qkv     = ws + 16 * M1;
    ushort_t* h2      = ws;
    ushort_t* ffbuf   = ws + 12 * M1;
    float*    bqkv    = (float*)d_out;
    ushort_t* vtbuf   = (ushort_t*)d_out;

    dim3 tb(32, 8);

    concat3_kernel<<<12, 256, 0, stream>>>(bq, bk, bv, bqkv);
    transpose_all_kernel<<<12288, tb, 0, stream>>>(
        Wq, Wk, Wv, Wo, W1, W2,
        qkvT, qkvT + M1, qkvT + 2 * M1, WoT, W1T, W2T);

    // h = LN1(x)
    ln_f32_kernel<<<4096, 256, 0, stream>>>(x, ln1s, ln1b, h);

    // qkv = h @ [Wq|Wk|Wv] + bqkv  (N=3072, 768 blocks)
    gemm_bt_kernel<<<dim3(24, 32), 256, 0, stream>>>(
        h, qkvT, bqkv, nullptr, qkv, nullptr, 4096, 3072, 1024, 1024, 0);

    // vt (per-head V^T) -> d_out (bqkv dead)
    transpose_v_kernel<<<dim3(64, 2, 32), tb, 0, stream>>>(qkv, vtbuf);

    // attention -> attnout; BQ=128, barrier-free, grid 512 blocks
    attn_kernel<<<dim3(16, 32), 256, 0, stream>>>(qkv, vtbuf, attnout);

    // outf = x (vt dead), then x2 = outf += attnout@Wo + bo (split-K 4)
    copy_f32_kernel<<<4096, 256, 0, stream>>>(x, outf);
    gemm_bt_atomic_kernel<<<dim3(8, 32, 4), 256, 0, stream>>>(
        attnout, WoT, bo, outf, 4096, 1024, 1024, 1024, 256);

    // h2 = LN2(x2)
    ln_f32_kernel<<<4096, 256, 0, stream>>>(outf, ln2s, ln2b, h2);

    // ffbuf = relu(h2 @ W1 + b1)  (N=4096, 1024 blocks)
    gemm_bt_kernel<<<dim3(32, 32), 256, 0, stream>>>(
        h2, W1T, b1, nullptr, ffbuf, nullptr, 4096, 4096, 1024, 1024, 1);

    // out = x2 += ffbuf @ W2 + b2  (split-K 4, 1024 blocks, atomic fp32)
    gemm_bt_atomic_kernel<<<dim3(8, 32, 4), 256, 0, stream>>>(
        ffbuf, W2T, b2, outf, 4096, 1024, 4096, 4096, 1024);
}

// Round 12
// 529.174 us; speedup vs baseline: 1.0795x; 1.0795x over previous
//
#include <hip/hip_runtime.h>

typedef unsigned short ushort_t;
typedef __attribute__((ext_vector_type(8))) __bf16 bf16x8;
typedef __attribute__((ext_vector_type(8))) unsigned short ushort8v;
typedef __attribute__((ext_vector_type(4))) float floatx4;

__device__ inline float b2f(ushort_t u) {
    union { unsigned int i; float f; } c; c.i = ((unsigned int)u) << 16; return c.f;
}
__device__ inline ushort_t f2b(float f) {
    union { float f; unsigned int i; } c; c.f = f;
    unsigned int i = c.i;
    unsigned int r = (i + 0x7FFFu + ((i >> 16) & 1u)) >> 16;
    return (ushort_t)r;
}
__device__ inline bf16x8 as_bf16x8(ushort8v u) { return __builtin_bit_cast(bf16x8, u); }

// Async global->LDS, 16 B per lane (m97). LDS dest = wave-uniform base +
// lane*16; LDS layout must be contiguous in lane order.
__device__ inline void load_lds16(const ushort_t* g, ushort_t* l) {
    __builtin_amdgcn_global_load_lds(
        (const __attribute__((address_space(1))) void*)g,
        (__attribute__((address_space(3))) void*)l, 16, 0, 0);
}

// XCD-aware block swizzle: HW round-robins consecutive block ids over 8 XCDs;
// map lid so each XCD (lid%8) owns one 128-col B strip (fits its 4MB L2,
// reused gridY times). Bijective when gridDim.x % 8 == 0.
__device__ inline void swizzle_mn(int gy, int* m0, int* n0) {
    int lid = blockIdx.x + blockIdx.y * gridDim.x;
    *n0 = ((lid & 7) + 8 * (lid / (8 * gy))) * 128;
    *m0 = ((lid >> 3) % gy) * 128;
}

// ---------------------------------------------------------------------------
// bias concat: o[0..3072) = bq | bk | bv
// ---------------------------------------------------------------------------
__global__ __launch_bounds__(256) void concat3_kernel(
    const float* __restrict__ a, const float* __restrict__ b,
    const float* __restrict__ c, float* __restrict__ o) {
    int t = blockIdx.x * 256 + threadIdx.x;
    if (t < 3072)
        o[t] = t < 1024 ? a[t] : (t < 2048 ? b[t - 1024] : c[t - 2048]);
}

// ---------------------------------------------------------------------------
// fp32 copy (x -> outf), float4 vectorized.
// ---------------------------------------------------------------------------
__global__ __launch_bounds__(256) void copy_f32_kernel(
    const float* __restrict__ src, float* __restrict__ dst) {
    size_t i = ((size_t)blockIdx.x * 256 + threadIdx.x) * 4;
    *(float4*)(dst + i) = *(const float4*)(src + i);
}

// ---------------------------------------------------------------------------
// ALL weight transposes in one dispatch. 12288 32x32 tiles, 1-D grid.
// out[c*R + r] = bf16(in[r*ld + c]).
// ---------------------------------------------------------------------------
__global__ __launch_bounds__(256) void transpose_all_kernel(
    const float* __restrict__ Wq, const float* __restrict__ Wk,
    const float* __restrict__ Wv, const float* __restrict__ Wo,
    const float* __restrict__ W1, const float* __restrict__ W2,
    ushort_t* __restrict__ dq, ushort_t* __restrict__ dk,
    ushort_t* __restrict__ dv, ushort_t* __restrict__ do_,
    ushort_t* __restrict__ d1, ushort_t* __restrict__ d2) {
    int t = blockIdx.x;
    const float* src; ushort_t* dst; int R, ld, tcx, tcy;
    if (t < 4096) {
        int id = t >> 10, u = t & 1023;
        tcx = u & 31; tcy = u >> 5; R = 1024; ld = 1024;
        src = id == 0 ? Wq : id == 1 ? Wk : id == 2 ? Wv : Wo;
        dst = id == 0 ? dq : id == 1 ? dk : id == 2 ? dv : do_;
    } else if (t < 8192) {
        int u = t - 4096;
        tcx = u & 127; tcy = u >> 7; R = 1024; ld = 4096;
        src = W1; dst = d1;
    } else {
        int u = t - 8192;
        tcx = u & 31; tcy = u >> 5; R = 4096; ld = 1024;
        src = W2; dst = d2;
    }
    __shared__ float tile[32][33];
    int tx = threadIdx.x, ty = threadIdx.y;
    int r0 = tcy * 32, c0 = tcx * 32;
#pragma unroll
    for (int i = 0; i < 32; i += 8)
        tile[ty + i][tx] = src[(size_t)(r0 + ty + i) * ld + c0 + tx];
    __syncthreads();
#pragma unroll
    for (int i = 0; i < 32; i += 8)
        dst[(size_t)(c0 + ty + i) * R + r0 + tx] = f2b(tile[tx][ty + i]);
}

// ---------------------------------------------------------------------------
// Per-head V transpose (bf16): qkv [B*S][3072] (V at col 2048+h*64) ->
// vt [bh][64][2048].  grid (S/32, 2, 32), block (32,8).
// ---------------------------------------------------------------------------
__global__ __launch_bounds__(256) void transpose_v_kernel(
    const ushort_t* __restrict__ qkv, ushort_t* __restrict__ vt) {
    __shared__ ushort_t tile[32][33];
    int tx = threadIdx.x, ty = threadIdx.y;
    int s0 = blockIdx.x * 32, d0 = blockIdx.y * 32;
    int bh = blockIdx.z, b = bh >> 4, h = bh & 15;
    const ushort_t* src = qkv + (size_t)b * 2048 * 3072 + 2048 + h * 64;
    ushort_t* dst = vt + (size_t)bh * 64 * 2048;
#pragma unroll
    for (int i = 0; i < 32; i += 8)
        tile[ty + i][tx] = src[(size_t)(s0 + ty + i) * 3072 + d0 + tx];
    __syncthreads();
#pragma unroll
    for (int i = 0; i < 32; i += 8)
        dst[(size_t)(d0 + ty + i) * 2048 + s0 + tx] = tile[tx][ty + i];
}

// ---------------------------------------------------------------------------
// LayerNorm: rows of 1024, fp32 in -> bf16 out.
// ---------------------------------------------------------------------------
__device__ inline float wave_sum(float s) {
#pragma unroll
    for (int o = 32; o > 0; o >>= 1) s += __shfl_xor(s, o);
    return s;
}

__global__ __launch_bounds__(256) void ln_f32_kernel(
    const float* __restrict__ x, const float* __restrict__ sc,
    const float* __restrict__ bi, ushort_t* __restrict__ out) {
    int row = blockIdx.x, t = threadIdx.x;
    const float* xr = x + (size_t)row * 1024;
    float4 u = *(const float4*)(xr + t * 4);
    float v0 = u.x, v1 = u.y, v2 = u.z, v3 = u.w;
    __shared__ float sm[8];
    int wv = t >> 6, lane = t & 63;
    float s = wave_sum(v0 + v1 + v2 + v3);
    if (lane == 0) sm[wv] = s;
    __syncthreads();
    float mean = (sm[0] + sm[1] + sm[2] + sm[3]) * (1.0f / 1024.0f);
    float d0 = v0 - mean, d1 = v1 - mean, d2 = v2 - mean, d3 = v3 - mean;
    float q = wave_sum(d0 * d0 + d1 * d1 + d2 * d2 + d3 * d3);
    if (lane == 0) sm[4 + wv] = q;
    __syncthreads();
    float var = (sm[4] + sm[5] + sm[6] + sm[7]) * (1.0f / 1024.0f);
    float rn = rsqrtf(var + 1e-6f);
    float4 us = *(const float4*)(sc + t * 4);
    float4 ub = *(const float4*)(bi + t * 4);
    ushort4 o;
    o.x = f2b(d0 * rn * us.x + ub.x);
    o.y = f2b(d1 * rn * us.y + ub.y);
    o.z = f2b(d2 * rn * us.z + ub.z);
    o.w = f2b(d3 * rn * us.w + ub.w);
    *(ushort4*)(out + (size_t)row * 1024 + t * 4) = o;
}

// ---------------------------------------------------------------------------
// GEMM: acc[M][N] = A[M][K] @ Bt[N][K]^T (bf16 in, fp32 acc).
// 128x128 tile, BK=64, global_load_lds staging, XCD-swizzled block map.
// op: 0: Cb=bf16(acc+bias)  1: Cb=bf16(relu(acc+bias))
//     2: Cf=acc+bias+resf   3: Cf=acc+resf      (resf may alias Cf)
// ---------------------------------------------------------------------------
__global__ __launch_bounds__(256) void gemm_bt_kernel(
    const ushort_t* __restrict__ A, const ushort_t* __restrict__ Bt,
    const float* __restrict__ bias, const float* __restrict__ resf,
    ushort_t* __restrict__ Cb, float* __restrict__ Cf,
    int M, int N, int K, int ldb, int op) {
    __shared__ __align__(16) ushort_t As[128 * 64];
    __shared__ __align__(16) ushort_t Bs[128 * 64];
    int tid = threadIdx.x;
    int m0, n0;
    swizzle_mn(gridDim.y, &m0, &n0);
    int wv = tid >> 6, lane = tid & 63;
    int wr = wv & 1, wc = wv >> 1;
    int mo = wr * 64, no = wc * 64;
    int quad = lane >> 4, l16 = lane & 15;
    int k8 = quad * 8;

    floatx4 acc[4][4] = {};

    for (int k0 = 0; k0 < K; k0 += 64) {
#pragma unroll
        for (int c = 0; c < 4; ++c) {
            int e = c * 2048 + tid * 8;
            int r = e >> 6, kk = e & 63;
            int wbase = c * 2048 + wv * 512;
            load_lds16(A + (size_t)(m0 + r) * K + k0 + kk, As + wbase);
            load_lds16(Bt + (size_t)(n0 + r) * ldb + k0 + kk, Bs + wbase);
        }
        __syncthreads();
#pragma unroll
        for (int h = 0; h < 2; ++h) {
            bf16x8 af[4], bfr[4];
#pragma unroll
            for (int i = 0; i < 4; ++i) {
                af[i]  = as_bf16x8(*(const ushort8v*)(As + (mo + i * 16 + l16) * 64 + h * 32 + k8));
                bfr[i] = as_bf16x8(*(const ushort8v*)(Bs + (no + i * 16 + l16) * 64 + h * 32 + k8));
            }
#pragma unroll
            for (int mi = 0; mi < 4; ++mi)
#pragma unroll
                for (int ni = 0; ni < 4; ++ni)
                    acc[mi][ni] = __builtin_amdgcn_mfma_f32_16x16x32_bf16(
                        af[mi], bfr[ni], acc[mi][ni], 0, 0, 0);
        }
        __syncthreads();
    }

#pragma unroll
    for (int mi = 0; mi < 4; ++mi) {
#pragma unroll
        for (int r = 0; r < 4; ++r) {
            int row = m0 + mo + mi * 16 + quad * 4 + r;
            size_t rowoff = (size_t)row * N;
#pragma unroll
            for (int ni = 0; ni < 4; ++ni) {
                int col = n0 + no + ni * 16 + l16;
                float val = acc[mi][ni][r];
                if (op != 3) val += bias[col];
                if (op == 1) val = fmaxf(val, 0.0f);
                if (op >= 2) {
                    val += resf[rowoff + col];
                    Cf[rowoff + col] = val;
                } else {
                    Cb[rowoff + col] = f2b(val);
                }
            }
        }
    }
}

// ---------------------------------------------------------------------------
// Split-K GEMM, atomic fp32 epilogue: Cf[m][n] += acc_z (+bias if z==0).
// XCD-swizzled. Cf pre-initialized with the residual term.
// ---------------------------------------------------------------------------
__global__ __launch_bounds__(256) void gemm_bt_atomic_kernel(
    const ushort_t* __restrict__ A, const ushort_t* __restrict__ Bt,
    const float* __restrict__ bias, float* __restrict__ Cf,
    int M, int N, int lda, int ldb, int Kc) {
    __shared__ __align__(16) ushort_t As[128 * 64];
    __shared__ __align__(16) ushort_t Bs[128 * 64];
    int tid = threadIdx.x;
    int m0, n0;
    swizzle_mn(gridDim.y, &m0, &n0);
    int kbase = blockIdx.z * Kc;
    int wv = tid >> 6, lane = tid & 63;
    int wr = wv & 1, wc = wv >> 1;
    int mo = wr * 64, no = wc * 64;
    int quad = lane >> 4, l16 = lane & 15;
    int k8 = quad * 8;

    floatx4 acc[4][4] = {};

    for (int k0 = kbase; k0 < kbase + Kc; k0 += 64) {
#pragma unroll
        for (int c = 0; c < 4; ++c) {
            int e = c * 2048 + tid * 8;
            int r = e >> 6, kk = e & 63;
            int wbase = c * 2048 + wv * 512;
            load_lds16(A + (size_t)(m0 + r) * lda + k0 + kk, As + wbase);
            load_lds16(Bt + (size_t)(n0 + r) * ldb + k0 + kk, Bs + wbase);
        }
        __syncthreads();
#pragma unroll
        for (int h = 0; h < 2; ++h) {
            bf16x8 af[4], bfr[4];
#pragma unroll
            for (int i = 0; i < 4; ++i) {
                af[i]  = as_bf16x8(*(const ushort8v*)(As + (mo + i * 16 + l16) * 64 + h * 32 + k8));
                bfr[i] = as_bf16x8(*(const ushort8v*)(Bs + (no + i * 16 + l16) * 64 + h * 32 + k8));
            }
#pragma unroll
            for (int mi = 0; mi < 4; ++mi)
#pragma unroll
                for (int ni = 0; ni < 4; ++ni)
                    acc[mi][ni] = __builtin_amdgcn_mfma_f32_16x16x32_bf16(
                        af[mi], bfr[ni], acc[mi][ni], 0, 0, 0);
        }
        __syncthreads();
    }

    bool addb = (blockIdx.z == 0) && (bias != nullptr);
#pragma unroll
    for (int mi = 0; mi < 4; ++mi) {
#pragma unroll
        for (int r = 0; r < 4; ++r) {
            int row = m0 + mo + mi * 16 + quad * 4 + r;
            size_t rowoff = (size_t)row * N;
#pragma unroll
            for (int ni = 0; ni < 4; ++ni) {
                int col = n0 + no + ni * 16 + l16;
                float val = acc[mi][ni][r];
                if (addb) val += bias[col];
                unsafeAtomicAdd(&Cf[rowoff + col], val);
            }
        }
    }
}

// ---------------------------------------------------------------------------
// Flash attention (round-10 proven version): LDS-staged K/V with register
// prefetch, shuffle-free softmax (row-sum via MFMA with ones), BQ=128.
// grid (S/128, B*H).  LDS-pipe-throughput-bound (~474 cyc/wave/iter model).
// ---------------------------------------------------------------------------
__global__ __launch_bounds__(256) void attn_kernel(
    const ushort_t* __restrict__ qkv, const ushort_t* __restrict__ vt,
    ushort_t* __restrict__ om) {
    const int LDQ = 3072, LDO = 1024;
    int bh = blockIdx.y;
    int b = bh >> 4, h = bh & 15;
    size_t qbase = (size_t)b * 2048 * LDQ + h * 64;
    size_t kbase = qbase + 1024;
    const ushort_t* vtp = vt + (size_t)bh * 64 * 2048;
    int q0 = blockIdx.x * 128;
    int tid = threadIdx.x, wv = tid >> 6, lane = tid & 63;
    int quad = lane >> 4, l16 = lane & 15;
    int k8 = quad * 8;

    __shared__ __align__(16) ushort_t Ks[64 * 72];
    __shared__ __align__(16) ushort_t Vs[64 * 72];
    __shared__ __align__(16) ushort_t Ps[4 * 32 * 76];
    ushort_t* ps = Ps + wv * 32 * 76;

    int sr0 = tid >> 3, scc0 = (tid & 7) * 8;
    int sr1 = sr0 + 32;

    bf16x8 qf[2][2];
#pragma unroll
    for (int mt = 0; mt < 2; ++mt) {
        const ushort_t* qptr = qkv + qbase + (size_t)(q0 + wv * 32 + mt * 16 + l16) * LDQ;
        qf[mt][0] = as_bf16x8(*(const ushort8v*)(qptr + k8));
        qf[mt][1] = as_bf16x8(*(const ushort8v*)(qptr + 32 + k8));
    }

    bf16x8 ones;
#pragma unroll
    for (int j = 0; j < 8; ++j) ones[j] = (__bf16)1.0f;

    floatx4 Oacc[2][4] = {};
    floatx4 lsum[2] = {};

    ushort8v kreg0, kreg1, vreg0, vreg1;
    kreg0 = *(const ushort8v*)(qkv + kbase + (size_t)sr0 * LDQ + scc0);
    kreg1 = *(const ushort8v*)(qkv + kbase + (size_t)sr1 * LDQ + scc0);
    vreg0 = *(const ushort8v*)(vtp + (size_t)sr0 * 2048 + scc0);
    vreg1 = *(const ushort8v*)(vtp + (size_t)sr1 * 2048 + scc0);

    for (int kb = 0; kb < 2048; kb += 64) {
        __syncthreads();
        *(ushort8v*)(Ks + sr0 * 72 + scc0) = kreg0;
        *(ushort8v*)(Ks + sr1 * 72 + scc0) = kreg1;
        *(ushort8v*)(Vs + sr0 * 72 + scc0) = vreg0;
        *(ushort8v*)(Vs + sr1 * 72 + scc0) = vreg1;
        __syncthreads();

        int nkb = (kb + 64 < 2048) ? kb + 64 : 0;
        kreg0 = *(const ushort8v*)(qkv + kbase + (size_t)(nkb + sr0) * LDQ + scc0);
        kreg1 = *(const ushort8v*)(qkv + kbase + (size_t)(nkb + sr1) * LDQ + scc0);
        vreg0 = *(const ushort8v*)(vtp + (size_t)sr0 * 2048 + nkb + scc0);
        vreg1 = *(const ushort8v*)(vtp + (size_t)sr1 * 2048 + nkb + scc0);

        bf16x8 kf[4][2];
#pragma unroll
        for (int kt = 0; kt < 4; ++kt)
#pragma unroll
            for (int ds = 0; ds < 2; ++ds)
                kf[kt][ds] = as_bf16x8(
                    *(const ushort8v*)(Ks + (kt * 16 + l16) * 72 + ds * 32 + k8));

        floatx4 sc[2][4];
#pragma unroll
        for (int mt = 0; mt < 2; ++mt)
#pragma unroll
            for (int kt = 0; kt < 4; ++kt) {
                floatx4 s = {0.0f, 0.0f, 0.0f, 0.0f};
                s = __builtin_amdgcn_mfma_f32_16x16x32_bf16(qf[mt][0], kf[kt][0], s, 0, 0, 0);
                s = __builtin_amdgcn_mfma_f32_16x16x32_bf16(qf[mt][1], kf[kt][1], s, 0, 0, 0);
                sc[mt][kt] = s;
            }

#pragma unroll
        for (int mt = 0; mt < 2; ++mt)
#pragma unroll
            for (int kt = 0; kt < 4; ++kt)
#pragma unroll
                for (int r = 0; r < 4; ++r)
                    ps[(mt * 16 + quad * 4 + r) * 76 + kt * 16 + l16] =
                        f2b(__expf(sc[mt][kt][r] * 0.125f));

        bf16x8 vf[4][2];
#pragma unroll
        for (int dt = 0; dt < 4; ++dt)
#pragma unroll
            for (int ks = 0; ks < 2; ++ks)
                vf[dt][ks] = as_bf16x8(
                    *(const ushort8v*)(Vs + (dt * 16 + l16) * 72 + ks * 32 + k8));
#pragma unroll
        for (int mt = 0; mt < 2; ++mt) {
            bf16x8 pf0 = as_bf16x8(*(const ushort8v*)(ps + (mt * 16 + l16) * 76 + k8));
            bf16x8 pf1 = as_bf16x8(*(const ushort8v*)(ps + (mt * 16 + l16) * 76 + 32 + k8));
#pragma unroll
            for (int dt = 0; dt < 4; ++dt) {
                Oacc[mt][dt] = __builtin_amdgcn_mfma_f32_16x16x32_bf16(pf0, vf[dt][0], Oacc[mt][dt], 0, 0, 0);
                Oacc[mt][dt] = __builtin_amdgcn_mfma_f32_16x16x32_bf16(pf1, vf[dt][1], Oacc[mt][dt], 0, 0, 0);
            }
            lsum[mt] = __builtin_amdgcn_mfma_f32_16x16x32_bf16(pf0, ones, lsum[mt], 0, 0, 0);
            lsum[mt] = __builtin_amdgcn_mfma_f32_16x16x32_bf16(pf1, ones, lsum[mt], 0, 0, 0);
        }
    }

#pragma unroll
    for (int mt = 0; mt < 2; ++mt)
#pragma unroll
        for (int r = 0; r < 4; ++r) {
            float inv = 1.0f / lsum[mt][r];
            size_t rowoff = (size_t)(b * 2048 + q0 + wv * 32 + mt * 16 + quad * 4 + r) * LDO + h * 64;
#pragma unroll
            for (int dt = 0; dt < 4; ++dt)
                om[rowoff + dt * 16 + l16] = f2b(Oacc[mt][dt][r] * inv);
        }
}

// ---------------------------------------------------------------------------
// Workspace map (bf16 elems, M1 = 1048576), peak 28M elems = 56 MB (proven):
//   qkvT [0,3M)  WoT [3M,4M)  W1T [4M,8M)  W2T [8M,12M)
//   h/attnout [12M,16M)   qkv [16M,28M)
//   h2 -> [0,4M) after qkvT/WoT die; ffbuf -> [12M,28M) after attnout/qkv die
// d_out timeline: bqkv (12 KB) -> vt (8 MB bf16) -> outf (x2 fp32 16 MB).
// ---------------------------------------------------------------------------
extern "C" void kernel_launch(void* const* d_in, const int* in_sizes, int n_in,
                              void* d_out, int out_size, void* d_ws, size_t ws_size,
                              hipStream_t stream) {
    const float* x    = (const float*)d_in[0];
    const float* Wq   = (const float*)d_in[1];
    const float* bq   = (const float*)d_in[2];
    const float* Wk   = (const float*)d_in[3];
    const float* bk   = (const float*)d_in[4];
    const float* Wv   = (const float*)d_in[5];
    const float* bv   = (const float*)d_in[6];
    const float* Wo   = (const float*)d_in[7];
    const float* bo   = (const float*)d_in[8];
    const float* W1   = (const float*)d_in[9];
    const float* b1   = (const float*)d_in[10];
    const float* W2   = (const float*)d_in[11];
    const float* b2   = (const float*)d_in[12];
    const float* ln1s = (const float*)d_in[13];
    const float* ln1b = (const float*)d_in[14];
    const float* ln2s = (const float*)d_in[15];
    const float* ln2b = (const float*)d_in[16];
    float*    outf = (float*)d_out;
    ushort_t* ws   = (ushort_t*)d_ws;

    const size_t M1 = 1048576;
    ushort_t* qkvT    = ws;
    ushort_t* WoT     = ws + 3 * M1;
    ushort_t* W1T     = ws + 4 * M1;
    ushort_t* W2T     = ws + 8 * M1;
    ushort_t* h       = ws + 12 * M1;
    ushort_t* attnout = ws + 12 * M1;
    ushort_t* qkv     = ws + 16 * M1;
    ushort_t* h2      = ws;
    ushort_t* ffbuf   = ws + 12 * M1;
    float*    bqkv    = (float*)d_out;
    ushort_t* vtbuf   = (ushort_t*)d_out;

    dim3 tb(32, 8);

    concat3_kernel<<<12, 256, 0, stream>>>(bq, bk, bv, bqkv);
    transpose_all_kernel<<<12288, tb, 0, stream>>>(
        Wq, Wk, Wv, Wo, W1, W2,
        qkvT, qkvT + M1, qkvT + 2 * M1, WoT, W1T, W2T);

    // h = LN1(x)
    ln_f32_kernel<<<4096, 256, 0, stream>>>(x, ln1s, ln1b, h);

    // qkv = h @ [Wq|Wk|Wv] + bqkv  (N=3072, 768 blocks, XCD-swizzled)
    gemm_bt_kernel<<<dim3(24, 32), 256, 0, stream>>>(
        h, qkvT, bqkv, nullptr, qkv, nullptr, 4096, 3072, 1024, 1024, 0);

    // vt (per-head V^T) -> d_out (bqkv dead)
    transpose_v_kernel<<<dim3(64, 2, 32), tb, 0, stream>>>(qkv, vtbuf);

    // attention -> attnout; BQ=128, grid 512 blocks
    attn_kernel<<<dim3(16, 32), 256, 0, stream>>>(qkv, vtbuf, attnout);

    // outf = x (vt dead), then x2 = outf += attnout@Wo + bo (split-K 4)
    copy_f32_kernel<<<4096, 256, 0, stream>>>(x, outf);
    gemm_bt_atomic_kernel<<<dim3(8, 32, 4), 256, 0, stream>>>(
        attnout, WoT, bo, outf, 4096, 1024, 1024, 1024, 256);

    // h2 = LN2(x2)
    ln_f32_kernel<<<4096, 256, 0, stream>>>(outf, ln2s, ln2b, h2);

    // ffbuf = relu(h2 @ W1 + b1)  (N=4096, 1024 blocks)
    gemm_bt_kernel<<<dim3(32, 32), 256, 0, stream>>>(
        h2, W1T, b1, nullptr, ffbuf, nullptr, 4096, 4096, 1024, 1024, 1);

    // out = x2 += ffbuf @ W2 + b2  (split-K 2, 512 blocks, atomic fp32)
    gemm_bt_atomic_kernel<<<dim3(8, 32, 2), 256, 0, stream>>>(
        ffbuf, W2T, b2, outf, 4096, 1024, 4096, 4096, 2048);
}

// Round 13
// 508.136 us; speedup vs baseline: 1.1242x; 1.0414x over previous
//
#include <hip/hip_runtime.h>

typedef unsigned short ushort_t;
typedef __attribute__((ext_vector_type(8))) __bf16 bf16x8;
typedef __attribute__((ext_vector_type(8))) unsigned short ushort8v;
typedef __attribute__((ext_vector_type(4))) float floatx4;

__device__ inline float b2f(ushort_t u) {
    union { unsigned int i; float f; } c; c.i = ((unsigned int)u) << 16; return c.f;
}
__device__ inline ushort_t f2b(float f) {
    union { float f; unsigned int i; } c; c.f = f;
    unsigned int i = c.i;
    unsigned int r = (i + 0x7FFFu + ((i >> 16) & 1u)) >> 16;
    return (ushort_t)r;
}
__device__ inline bf16x8 as_bf16x8(ushort8v u) { return __builtin_bit_cast(bf16x8, u); }

// Async global->LDS, 16 B per lane (m97). LDS dest = wave-uniform base +
// lane*16; LDS layout must be contiguous in lane order.
__device__ inline void load_lds16(const ushort_t* g, ushort_t* l) {
    __builtin_amdgcn_global_load_lds(
        (const __attribute__((address_space(1))) void*)g,
        (__attribute__((address_space(3))) void*)l, 16, 0, 0);
}

// ---------------------------------------------------------------------------
// bias concat: o[0..3072) = bq | bk | bv
// ---------------------------------------------------------------------------
__global__ __launch_bounds__(256) void concat3_kernel(
    const float* __restrict__ a, const float* __restrict__ b,
    const float* __restrict__ c, float* __restrict__ o) {
    int t = blockIdx.x * 256 + threadIdx.x;
    if (t < 3072)
        o[t] = t < 1024 ? a[t] : (t < 2048 ? b[t - 1024] : c[t - 2048]);
}

// ---------------------------------------------------------------------------
// fp32 copy (x -> outf), float4 vectorized.
// ---------------------------------------------------------------------------
__global__ __launch_bounds__(256) void copy_f32_kernel(
    const float* __restrict__ src, float* __restrict__ dst) {
    size_t i = ((size_t)blockIdx.x * 256 + threadIdx.x) * 4;
    *(float4*)(dst + i) = *(const float4*)(src + i);
}

// ---------------------------------------------------------------------------
// ALL weight transposes in one dispatch. 12288 32x32 tiles, 1-D grid.
// out[c*R + r] = bf16(in[r*ld + c]).
// ---------------------------------------------------------------------------
__global__ __launch_bounds__(256) void transpose_all_kernel(
    const float* __restrict__ Wq, const float* __restrict__ Wk,
    const float* __restrict__ Wv, const float* __restrict__ Wo,
    const float* __restrict__ W1, const float* __restrict__ W2,
    ushort_t* __restrict__ dq, ushort_t* __restrict__ dk,
    ushort_t* __restrict__ dv, ushort_t* __restrict__ do_,
    ushort_t* __restrict__ d1, ushort_t* __restrict__ d2) {
    int t = blockIdx.x;
    const float* src; ushort_t* dst; int R, ld, tcx, tcy;
    if (t < 4096) {
        int id = t >> 10, u = t & 1023;
        tcx = u & 31; tcy = u >> 5; R = 1024; ld = 1024;
        src = id == 0 ? Wq : id == 1 ? Wk : id == 2 ? Wv : Wo;
        dst = id == 0 ? dq : id == 1 ? dk : id == 2 ? dv : do_;
    } else if (t < 8192) {
        int u = t - 4096;
        tcx = u & 127; tcy = u >> 7; R = 1024; ld = 4096;
        src = W1; dst = d1;
    } else {
        int u = t - 8192;
        tcx = u & 31; tcy = u >> 5; R = 4096; ld = 1024;
        src = W2; dst = d2;
    }
    __shared__ float tile[32][33];
    int tx = threadIdx.x, ty = threadIdx.y;
    int r0 = tcy * 32, c0 = tcx * 32;
#pragma unroll
    for (int i = 0; i < 32; i += 8)
        tile[ty + i][tx] = src[(size_t)(r0 + ty + i) * ld + c0 + tx];
    __syncthreads();
#pragma unroll
    for (int i = 0; i < 32; i += 8)
        dst[(size_t)(c0 + ty + i) * R + r0 + tx] = f2b(tile[tx][ty + i]);
}

// ---------------------------------------------------------------------------
// Per-head V transpose (bf16): qkv [B*S][3072] (V at col 2048+h*64) ->
// vt [bh][64][2048].  grid (S/32, 2, 32), block (32,8).
// ---------------------------------------------------------------------------
__global__ __launch_bounds__(256) void transpose_v_kernel(
    const ushort_t* __restrict__ qkv, ushort_t* __restrict__ vt) {
    __shared__ ushort_t tile[32][33];
    int tx = threadIdx.x, ty = threadIdx.y;
    int s0 = blockIdx.x * 32, d0 = blockIdx.y * 32;
    int bh = blockIdx.z, b = bh >> 4, h = bh & 15;
    const ushort_t* src = qkv + (size_t)b * 2048 * 3072 + 2048 + h * 64;
    ushort_t* dst = vt + (size_t)bh * 64 * 2048;
#pragma unroll
    for (int i = 0; i < 32; i += 8)
        tile[ty + i][tx] = src[(size_t)(s0 + ty + i) * 3072 + d0 + tx];
    __syncthreads();
#pragma unroll
    for (int i = 0; i < 32; i += 8)
        dst[(size_t)(d0 + ty + i) * 2048 + s0 + tx] = tile[tx][ty + i];
}

// ---------------------------------------------------------------------------
// LayerNorm: rows of 1024, fp32 in -> bf16 out.
// ---------------------------------------------------------------------------
__device__ inline float wave_sum(float s) {
#pragma unroll
    for (int o = 32; o > 0; o >>= 1) s += __shfl_xor(s, o);
    return s;
}

__global__ __launch_bounds__(256) void ln_f32_kernel(
    const float* __restrict__ x, const float* __restrict__ sc,
    const float* __restrict__ bi, ushort_t* __restrict__ out) {
    int row = blockIdx.x, t = threadIdx.x;
    const float* xr = x + (size_t)row * 1024;
    float4 u = *(const float4*)(xr + t * 4);
    float v0 = u.x, v1 = u.y, v2 = u.z, v3 = u.w;
    __shared__ float sm[8];
    int wv = t >> 6, lane = t & 63;
    float s = wave_sum(v0 + v1 + v2 + v3);
    if (lane == 0) sm[wv] = s;
    __syncthreads();
    float mean = (sm[0] + sm[1] + sm[2] + sm[3]) * (1.0f / 1024.0f);
    float d0 = v0 - mean, d1 = v1 - mean, d2 = v2 - mean, d3 = v3 - mean;
    float q = wave_sum(d0 * d0 + d1 * d1 + d2 * d2 + d3 * d3);
    if (lane == 0) sm[4 + wv] = q;
    __syncthreads();
    float var = (sm[4] + sm[5] + sm[6] + sm[7]) * (1.0f / 1024.0f);
    float rn = rsqrtf(var + 1e-6f);
    float4 us = *(const float4*)(sc + t * 4);
    float4 ub = *(const float4*)(bi + t * 4);
    ushort4 o;
    o.x = f2b(d0 * rn * us.x + ub.x);
    o.y = f2b(d1 * rn * us.y + ub.y);
    o.z = f2b(d2 * rn * us.z + ub.z);
    o.w = f2b(d3 * rn * us.w + ub.w);
    *(ushort4*)(out + (size_t)row * 1024 + t * 4) = o;
}

// ---------------------------------------------------------------------------
// GEMM: acc[M][N] = A[M][K] @ Bt[N][K]^T (bf16 in, fp32 acc).
// 128x128 tile, BK=64, global_load_lds staging, unpadded [128][64] LDS.
// op: 0: Cb=bf16(acc+bias)  1: Cb=bf16(relu(acc+bias))
//     2: Cf=acc+bias+resf   3: Cf=acc+resf      (resf may alias Cf)
// ---------------------------------------------------------------------------
__global__ __launch_bounds__(256) void gemm_bt_kernel(
    const ushort_t* __restrict__ A, const ushort_t* __restrict__ Bt,
    const float* __restrict__ bias, const float* __restrict__ resf,
    ushort_t* __restrict__ Cb, float* __restrict__ Cf,
    int M, int N, int K, int ldb, int op) {
    __shared__ __align__(16) ushort_t As[128 * 64];
    __shared__ __align__(16) ushort_t Bs[128 * 64];
    int tid = threadIdx.x;
    int m0 = blockIdx.y * 128, n0 = blockIdx.x * 128;
    int wv = tid >> 6, lane = tid & 63;
    int wr = wv & 1, wc = wv >> 1;
    int mo = wr * 64, no = wc * 64;
    int quad = lane >> 4, l16 = lane & 15;
    int k8 = quad * 8;

    floatx4 acc[4][4] = {};

    for (int k0 = 0; k0 < K; k0 += 64) {
#pragma unroll
        for (int c = 0; c < 4; ++c) {
            int e = c * 2048 + tid * 8;
            int r = e >> 6, kk = e & 63;
            int wbase = c * 2048 + wv * 512;
            load_lds16(A + (size_t)(m0 + r) * K + k0 + kk, As + wbase);
            load_lds16(Bt + (size_t)(n0 + r) * ldb + k0 + kk, Bs + wbase);
        }
        __syncthreads();
#pragma unroll
        for (int h = 0; h < 2; ++h) {
            bf16x8 af[4], bfr[4];
#pragma unroll
            for (int i = 0; i < 4; ++i) {
                af[i]  = as_bf16x8(*(const ushort8v*)(As + (mo + i * 16 + l16) * 64 + h * 32 + k8));
                bfr[i] = as_bf16x8(*(const ushort8v*)(Bs + (no + i * 16 + l16) * 64 + h * 32 + k8));
            }
#pragma unroll
            for (int mi = 0; mi < 4; ++mi)
#pragma unroll
                for (int ni = 0; ni < 4; ++ni)
                    acc[mi][ni] = __builtin_amdgcn_mfma_f32_16x16x32_bf16(
                        af[mi], bfr[ni], acc[mi][ni], 0, 0, 0);
        }
        __syncthreads();
    }

#pragma unroll
    for (int mi = 0; mi < 4; ++mi) {
#pragma unroll
        for (int r = 0; r < 4; ++r) {
            int row = m0 + mo + mi * 16 + quad * 4 + r;
            size_t rowoff = (size_t)row * N;
#pragma unroll
            for (int ni = 0; ni < 4; ++ni) {
                int col = n0 + no + ni * 16 + l16;
                float val = acc[mi][ni][r];
                if (op != 3) val += bias[col];
                if (op == 1) val = fmaxf(val, 0.0f);
                if (op >= 2) {
                    val += resf[rowoff + col];
                    Cf[rowoff + col] = val;
                } else {
                    Cb[rowoff + col] = f2b(val);
                }
            }
        }
    }
}

// ---------------------------------------------------------------------------
// Split-K GEMM, atomic fp32 epilogue: Cf[m][n] += acc_z (+bias if z==0).
// Cf pre-initialized with the residual term.
// ---------------------------------------------------------------------------
__global__ __launch_bounds__(256) void gemm_bt_atomic_kernel(
    const ushort_t* __restrict__ A, const ushort_t* __restrict__ Bt,
    const float* __restrict__ bias, float* __restrict__ Cf,
    int M, int N, int lda, int ldb, int Kc) {
    __shared__ __align__(16) ushort_t As[128 * 64];
    __shared__ __align__(16) ushort_t Bs[128 * 64];
    int tid = threadIdx.x;
    int m0 = blockIdx.y * 128, n0 = blockIdx.x * 128;
    int kbase = blockIdx.z * Kc;
    int wv = tid >> 6, lane = tid & 63;
    int wr = wv & 1, wc = wv >> 1;
    int mo = wr * 64, no = wc * 64;
    int quad = lane >> 4, l16 = lane & 15;
    int k8 = quad * 8;

    floatx4 acc[4][4] = {};

    for (int k0 = kbase; k0 < kbase + Kc; k0 += 64) {
#pragma unroll
        for (int c = 0; c < 4; ++c) {
            int e = c * 2048 + tid * 8;
            int r = e >> 6, kk = e & 63;
            int wbase = c * 2048 + wv * 512;
            load_lds16(A + (size_t)(m0 + r) * lda + k0 + kk, As + wbase);
            load_lds16(Bt + (size_t)(n0 + r) * ldb + k0 + kk, Bs + wbase);
        }
        __syncthreads();
#pragma unroll
        for (int h = 0; h < 2; ++h) {
            bf16x8 af[4], bfr[4];
#pragma unroll
            for (int i = 0; i < 4; ++i) {
                af[i]  = as_bf16x8(*(const ushort8v*)(As + (mo + i * 16 + l16) * 64 + h * 32 + k8));
                bfr[i] = as_bf16x8(*(const ushort8v*)(Bs + (no + i * 16 + l16) * 64 + h * 32 + k8));
            }
#pragma unroll
            for (int mi = 0; mi < 4; ++mi)
#pragma unroll
                for (int ni = 0; ni < 4; ++ni)
                    acc[mi][ni] = __builtin_amdgcn_mfma_f32_16x16x32_bf16(
                        af[mi], bfr[ni], acc[mi][ni], 0, 0, 0);
        }
        __syncthreads();
    }

    bool addb = (blockIdx.z == 0) && (bias != nullptr);
#pragma unroll
    for (int mi = 0; mi < 4; ++mi) {
#pragma unroll
        for (int r = 0; r < 4; ++r) {
            int row = m0 + mo + mi * 16 + quad * 4 + r;
            size_t rowoff = (size_t)row * N;
#pragma unroll
            for (int ni = 0; ni < 4; ++ni) {
                int col = n0 + no + ni * 16 + l16;
                float val = acc[mi][ni][r];
                if (addb) val += bias[col];
                unsafeAtomicAdd(&Cf[rowoff + col], val);
            }
        }
    }
}

// ---------------------------------------------------------------------------
// Flash attention. LDS-staged K/V + register prefetch; shuffle-free softmax
// (row-sum via MFMA with ones); BQ=128.  NEW: QK^T computed TRANSPOSED
// (A=kf, B=qf -> S^T in C-layout), so each lane's 4 acc registers are 4
// CONSECUTIVE k for one q-row -> P store packs into ushort4 ds_write_b64:
// 8 packed writes/wave/iter vs 32 scalar (LDS-pipe-bound fix; 474->~337
// cyc/wave/iter model). Ps layout [q][k] stride 76 unchanged -> PV reads
// and lsum identical. grid (S/128, B*H).
// ---------------------------------------------------------------------------
__global__ __launch_bounds__(256) void attn_kernel(
    const ushort_t* __restrict__ qkv, const ushort_t* __restrict__ vt,
    ushort_t* __restrict__ om) {
    const int LDQ = 3072, LDO = 1024;
    int bh = blockIdx.y;
    int b = bh >> 4, h = bh & 15;
    size_t qbase = (size_t)b * 2048 * LDQ + h * 64;
    size_t kbase = qbase + 1024;
    const ushort_t* vtp = vt + (size_t)bh * 64 * 2048;
    int q0 = blockIdx.x * 128;
    int tid = threadIdx.x, wv = tid >> 6, lane = tid & 63;
    int quad = lane >> 4, l16 = lane & 15;
    int k8 = quad * 8;

    __shared__ __align__(16) ushort_t Ks[64 * 72];
    __shared__ __align__(16) ushort_t Vs[64 * 72];
    __shared__ __align__(16) ushort_t Ps[4 * 32 * 76];
    ushort_t* ps = Ps + wv * 32 * 76;

    int sr0 = tid >> 3, scc0 = (tid & 7) * 8;
    int sr1 = sr0 + 32;

    bf16x8 qf[2][2];
#pragma unroll
    for (int mt = 0; mt < 2; ++mt) {
        const ushort_t* qptr = qkv + qbase + (size_t)(q0 + wv * 32 + mt * 16 + l16) * LDQ;
        qf[mt][0] = as_bf16x8(*(const ushort8v*)(qptr + k8));
        qf[mt][1] = as_bf16x8(*(const ushort8v*)(qptr + 32 + k8));
    }

    bf16x8 ones;
#pragma unroll
    for (int j = 0; j < 8; ++j) ones[j] = (__bf16)1.0f;

    floatx4 Oacc[2][4] = {};
    floatx4 lsum[2] = {};

    ushort8v kreg0, kreg1, vreg0, vreg1;
    kreg0 = *(const ushort8v*)(qkv + kbase + (size_t)sr0 * LDQ + scc0);
    kreg1 = *(const ushort8v*)(qkv + kbase + (size_t)sr1 * LDQ + scc0);
    vreg0 = *(const ushort8v*)(vtp + (size_t)sr0 * 2048 + scc0);
    vreg1 = *(const ushort8v*)(vtp + (size_t)sr1 * 2048 + scc0);

    for (int kb = 0; kb < 2048; kb += 64) {
        __syncthreads();
        *(ushort8v*)(Ks + sr0 * 72 + scc0) = kreg0;
        *(ushort8v*)(Ks + sr1 * 72 + scc0) = kreg1;
        *(ushort8v*)(Vs + sr0 * 72 + scc0) = vreg0;
        *(ushort8v*)(Vs + sr1 * 72 + scc0) = vreg1;
        __syncthreads();

        int nkb = (kb + 64 < 2048) ? kb + 64 : 0;
        kreg0 = *(const ushort8v*)(qkv + kbase + (size_t)(nkb + sr0) * LDQ + scc0);
        kreg1 = *(const ushort8v*)(qkv + kbase + (size_t)(nkb + sr1) * LDQ + scc0);
        vreg0 = *(const ushort8v*)(vtp + (size_t)sr0 * 2048 + nkb + scc0);
        vreg1 = *(const ushort8v*)(vtp + (size_t)sr1 * 2048 + nkb + scc0);

        bf16x8 kf[4][2];
#pragma unroll
        for (int kt = 0; kt < 4; ++kt)
#pragma unroll
            for (int ds = 0; ds < 2; ++ds)
                kf[kt][ds] = as_bf16x8(
                    *(const ushort8v*)(Ks + (kt * 16 + l16) * 72 + ds * 32 + k8));

        // S^T = K·Q^T: sc[mt][kt][r] = S[q=l16][k = kt*16 + quad*4 + r]
        floatx4 sc[2][4];
#pragma unroll
        for (int mt = 0; mt < 2; ++mt)
#pragma unroll
            for (int kt = 0; kt < 4; ++kt) {
                floatx4 s = {0.0f, 0.0f, 0.0f, 0.0f};
                s = __builtin_amdgcn_mfma_f32_16x16x32_bf16(kf[kt][0], qf[mt][0], s, 0, 0, 0);
                s = __builtin_amdgcn_mfma_f32_16x16x32_bf16(kf[kt][1], qf[mt][1], s, 0, 0, 0);
                sc[mt][kt] = s;
            }

        // P = exp(s/8), packed 4-consecutive-k store (ds_write_b64)
#pragma unroll
        for (int mt = 0; mt < 2; ++mt)
#pragma unroll
            for (int kt = 0; kt < 4; ++kt) {
                ushort4 pk;
                pk.x = f2b(__expf(sc[mt][kt][0] * 0.125f));
                pk.y = f2b(__expf(sc[mt][kt][1] * 0.125f));
                pk.z = f2b(__expf(sc[mt][kt][2] * 0.125f));
                pk.w = f2b(__expf(sc[mt][kt][3] * 0.125f));
                *(ushort4*)(ps + (mt * 16 + l16) * 76 + kt * 16 + quad * 4) = pk;
            }

        bf16x8 vf[4][2];
#pragma unroll
        for (int dt = 0; dt < 4; ++dt)
#pragma unroll
            for (int ks = 0; ks < 2; ++ks)
                vf[dt][ks] = as_bf16x8(
                    *(const ushort8v*)(Vs + (dt * 16 + l16) * 72 + ks * 32 + k8));
#pragma unroll
        for (int mt = 0; mt < 2; ++mt) {
            bf16x8 pf0 = as_bf16x8(*(const ushort8v*)(ps + (mt * 16 + l16) * 76 + k8));
            bf16x8 pf1 = as_bf16x8(*(const ushort8v*)(ps + (mt * 16 + l16) * 76 + 32 + k8));
#pragma unroll
            for (int dt = 0; dt < 4; ++dt) {
                Oacc[mt][dt] = __builtin_amdgcn_mfma_f32_16x16x32_bf16(pf0, vf[dt][0], Oacc[mt][dt], 0, 0, 0);
                Oacc[mt][dt] = __builtin_amdgcn_mfma_f32_16x16x32_bf16(pf1, vf[dt][1], Oacc[mt][dt], 0, 0, 0);
            }
            lsum[mt] = __builtin_amdgcn_mfma_f32_16x16x32_bf16(pf0, ones, lsum[mt], 0, 0, 0);
            lsum[mt] = __builtin_amdgcn_mfma_f32_16x16x32_bf16(pf1, ones, lsum[mt], 0, 0, 0);
        }
    }

#pragma unroll
    for (int mt = 0; mt < 2; ++mt)
#pragma unroll
        for (int r = 0; r < 4; ++r) {
            float inv = 1.0f / lsum[mt][r];
            size_t rowoff = (size_t)(b * 2048 + q0 + wv * 32 + mt * 16 + quad * 4 + r) * LDO + h * 64;
#pragma unroll
            for (int dt = 0; dt < 4; ++dt)
                om[rowoff + dt * 16 + l16] = f2b(Oacc[mt][dt][r] * inv);
        }
}

// ---------------------------------------------------------------------------
// Workspace map (bf16 elems, M1 = 1048576), peak 28M elems = 56 MB (proven):
//   qkvT [0,3M)  WoT [3M,4M)  W1T [4M,8M)  W2T [8M,12M)
//   h/attnout [12M,16M)   qkv [16M,28M)
//   h2 -> [0,4M) after qkvT/WoT die; ffbuf -> [12M,28M) after attnout/qkv die
// d_out timeline: bqkv (12 KB) -> vt (8 MB bf16) -> outf (x2 fp32 16 MB).
// ---------------------------------------------------------------------------
extern "C" void kernel_launch(void* const* d_in, const int* in_sizes, int n_in,
                              void* d_out, int out_size, void* d_ws, size_t ws_size,
                              hipStream_t stream) {
    const float* x    = (const float*)d_in[0];
    const float* Wq   = (const float*)d_in[1];
    const float* bq   = (const float*)d_in[2];
    const float* Wk   = (const float*)d_in[3];
    const float* bk   = (const float*)d_in[4];
    const float* Wv   = (const float*)d_in[5];
    const float* bv   = (const float*)d_in[6];
    const float* Wo   = (const float*)d_in[7];
    const float* bo   = (const float*)d_in[8];
    const float* W1   = (const float*)d_in[9];
    const float* b1   = (const float*)d_in[10];
    const float* W2   = (const float*)d_in[11];
    const float* b2   = (const float*)d_in[12];
    const float* ln1s = (const float*)d_in[13];
    const float* ln1b = (const float*)d_in[14];
    const float* ln2s = (const float*)d_in[15];
    const float* ln2b = (const float*)d_in[16];
    float*    outf = (float*)d_out;
    ushort_t* ws   = (ushort_t*)d_ws;

    const size_t M1 = 1048576;
    ushort_t* qkvT    = ws;
    ushort_t* WoT     = ws + 3 * M1;
    ushort_t* W1T     = ws + 4 * M1;
    ushort_t* W2T     = ws + 8 * M1;
    ushort_t* h       = ws + 12 * M1;
    ushort_t* attnout = ws + 12 * M1;
    ushort_t* qkv     = ws + 16 * M1;
    ushort_t* h2      = ws;
    ushort_t* ffbuf   = ws + 12 * M1;
    float*    bqkv    = (float*)d_out;
    ushort_t* vtbuf   = (ushort_t*)d_out;

    dim3 tb(32, 8);

    concat3_kernel<<<12, 256, 0, stream>>>(bq, bk, bv, bqkv);
    transpose_all_kernel<<<12288, tb, 0, stream>>>(
        Wq, Wk, Wv, Wo, W1, W2,
        qkvT, qkvT + M1, qkvT + 2 * M1, WoT, W1T, W2T);

    // h = LN1(x)
    ln_f32_kernel<<<4096, 256, 0, stream>>>(x, ln1s, ln1b, h);

    // qkv = h @ [Wq|Wk|Wv] + bqkv  (N=3072, 768 blocks)
    gemm_bt_kernel<<<dim3(24, 32), 256, 0, stream>>>(
        h, qkvT, bqkv, nullptr, qkv, nullptr, 4096, 3072, 1024, 1024, 0);

    // vt (per-head V^T) -> d_out (bqkv dead)
    transpose_v_kernel<<<dim3(64, 2, 32), tb, 0, stream>>>(qkv, vtbuf);

    // attention -> attnout; BQ=128, grid 512 blocks
    attn_kernel<<<dim3(16, 32), 256, 0, stream>>>(qkv, vtbuf, attnout);

    // outf = x (vt dead), then x2 = outf += attnout@Wo + bo (split-K 4)
    copy_f32_kernel<<<4096, 256, 0, stream>>>(x, outf);
    gemm_bt_atomic_kernel<<<dim3(8, 32, 4), 256, 0, stream>>>(
        attnout, WoT, bo, outf, 4096, 1024, 1024, 1024, 256);

    // h2 = LN2(x2)
    ln_f32_kernel<<<4096, 256, 0, stream>>>(outf, ln2s, ln2b, h2);

    // ffbuf = relu(h2 @ W1 + b1)  (N=4096, 1024 blocks)
    gemm_bt_kernel<<<dim3(32, 32), 256, 0, stream>>>(
        h2, W1T, b1, nullptr, ffbuf, nullptr, 4096, 4096, 1024, 1024, 1);

    // out = x2 += ffbuf @ W2 + b2  (split-K 2, 512 blocks, atomic fp32)
    gemm_bt_atomic_kernel<<<dim3(8, 32, 2), 256, 0, stream>>>(
        ffbuf, W2T, b2, outf, 4096, 1024, 4096, 4096, 2048);
}

// Round 14
// 494.422 us; speedup vs baseline: 1.1554x; 1.0277x over previous
//
#include <hip/hip_runtime.h>

typedef unsigned short ushort_t;
typedef __attribute__((ext_vector_type(8))) __bf16 bf16x8;
typedef __attribute__((ext_vector_type(4))) __bf16 bf16x4;
typedef __attribute__((ext_vector_type(8))) unsigned short ushort8v;
typedef __attribute__((ext_vector_type(4))) float floatx4;

__device__ inline float b2f(ushort_t u) {
    union { unsigned int i; float f; } c; c.i = ((unsigned int)u) << 16; return c.f;
}
__device__ inline ushort_t f2b(float f) {
    union { float f; unsigned int i; } c; c.f = f;
    unsigned int i = c.i;
    unsigned int r = (i + 0x7FFFu + ((i >> 16) & 1u)) >> 16;
    return (ushort_t)r;
}
__device__ inline bf16x8 as_bf16x8(ushort8v u) { return __builtin_bit_cast(bf16x8, u); }

// Async global->LDS, 16 B per lane (m97). LDS dest = wave-uniform base +
// lane*16; LDS layout must be contiguous in lane order.
__device__ inline void load_lds16(const ushort_t* g, ushort_t* l) {
    __builtin_amdgcn_global_load_lds(
        (const __attribute__((address_space(1))) void*)g,
        (__attribute__((address_space(3))) void*)l, 16, 0, 0);
}

// ---------------------------------------------------------------------------
// bias concat: o[0..3072) = bq | bk | bv
// ---------------------------------------------------------------------------
__global__ __launch_bounds__(256) void concat3_kernel(
    const float* __restrict__ a, const float* __restrict__ b,
    const float* __restrict__ c, float* __restrict__ o) {
    int t = blockIdx.x * 256 + threadIdx.x;
    if (t < 3072)
        o[t] = t < 1024 ? a[t] : (t < 2048 ? b[t - 1024] : c[t - 2048]);
}

// ---------------------------------------------------------------------------
// fp32 copy (x -> outf), float4 vectorized.
// ---------------------------------------------------------------------------
__global__ __launch_bounds__(256) void copy_f32_kernel(
    const float* __restrict__ src, float* __restrict__ dst) {
    size_t i = ((size_t)blockIdx.x * 256 + threadIdx.x) * 4;
    *(float4*)(dst + i) = *(const float4*)(src + i);
}

// ---------------------------------------------------------------------------
// ALL weight transposes in one dispatch. 12288 32x32 tiles, 1-D grid.
// out[c*R + r] = bf16(in[r*ld + c]).
// ---------------------------------------------------------------------------
__global__ __launch_bounds__(256) void transpose_all_kernel(
    const float* __restrict__ Wq, const float* __restrict__ Wk,
    const float* __restrict__ Wv, const float* __restrict__ Wo,
    const float* __restrict__ W1, const float* __restrict__ W2,
    ushort_t* __restrict__ dq, ushort_t* __restrict__ dk,
    ushort_t* __restrict__ dv, ushort_t* __restrict__ do_,
    ushort_t* __restrict__ d1, ushort_t* __restrict__ d2) {
    int t = blockIdx.x;
    const float* src; ushort_t* dst; int R, ld, tcx, tcy;
    if (t < 4096) {
        int id = t >> 10, u = t & 1023;
        tcx = u & 31; tcy = u >> 5; R = 1024; ld = 1024;
        src = id == 0 ? Wq : id == 1 ? Wk : id == 2 ? Wv : Wo;
        dst = id == 0 ? dq : id == 1 ? dk : id == 2 ? dv : do_;
    } else if (t < 8192) {
        int u = t - 4096;
        tcx = u & 127; tcy = u >> 7; R = 1024; ld = 4096;
        src = W1; dst = d1;
    } else {
        int u = t - 8192;
        tcx = u & 31; tcy = u >> 5; R = 4096; ld = 1024;
        src = W2; dst = d2;
    }
    __shared__ float tile[32][33];
    int tx = threadIdx.x, ty = threadIdx.y;
    int r0 = tcy * 32, c0 = tcx * 32;
#pragma unroll
    for (int i = 0; i < 32; i += 8)
        tile[ty + i][tx] = src[(size_t)(r0 + ty + i) * ld + c0 + tx];
    __syncthreads();
#pragma unroll
    for (int i = 0; i < 32; i += 8)
        dst[(size_t)(c0 + ty + i) * R + r0 + tx] = f2b(tile[tx][ty + i]);
}

// ---------------------------------------------------------------------------
// Per-head V transpose (bf16): qkv [B*S][3072] (V at col 2048+h*64) ->
// vt [bh][64][2048].  grid (S/32, 2, 32), block (32,8).
// ---------------------------------------------------------------------------
__global__ __launch_bounds__(256) void transpose_v_kernel(
    const ushort_t* __restrict__ qkv, ushort_t* __restrict__ vt) {
    __shared__ ushort_t tile[32][33];
    int tx = threadIdx.x, ty = threadIdx.y;
    int s0 = blockIdx.x * 32, d0 = blockIdx.y * 32;
    int bh = blockIdx.z, b = bh >> 4, h = bh & 15;
    const ushort_t* src = qkv + (size_t)b * 2048 * 3072 + 2048 + h * 64;
    ushort_t* dst = vt + (size_t)bh * 64 * 2048;
#pragma unroll
    for (int i = 0; i < 32; i += 8)
        tile[ty + i][tx] = src[(size_t)(s0 + ty + i) * 3072 + d0 + tx];
    __syncthreads();
#pragma unroll
    for (int i = 0; i < 32; i += 8)
        dst[(size_t)(d0 + ty + i) * 2048 + s0 + tx] = tile[tx][ty + i];
}

// ---------------------------------------------------------------------------
// LayerNorm: rows of 1024, fp32 in -> bf16 out.
// ---------------------------------------------------------------------------
__device__ inline float wave_sum(float s) {
#pragma unroll
    for (int o = 32; o > 0; o >>= 1) s += __shfl_xor(s, o);
    return s;
}

__global__ __launch_bounds__(256) void ln_f32_kernel(
    const float* __restrict__ x, const float* __restrict__ sc,
    const float* __restrict__ bi, ushort_t* __restrict__ out) {
    int row = blockIdx.x, t = threadIdx.x;
    const float* xr = x + (size_t)row * 1024;
    float4 u = *(const float4*)(xr + t * 4);
    float v0 = u.x, v1 = u.y, v2 = u.z, v3 = u.w;
    __shared__ float sm[8];
    int wv = t >> 6, lane = t & 63;
    float s = wave_sum(v0 + v1 + v2 + v3);
    if (lane == 0) sm[wv] = s;
    __syncthreads();
    float mean = (sm[0] + sm[1] + sm[2] + sm[3]) * (1.0f / 1024.0f);
    float d0 = v0 - mean, d1 = v1 - mean, d2 = v2 - mean, d3 = v3 - mean;
    float q = wave_sum(d0 * d0 + d1 * d1 + d2 * d2 + d3 * d3);
    if (lane == 0) sm[4 + wv] = q;
    __syncthreads();
    float var = (sm[4] + sm[5] + sm[6] + sm[7]) * (1.0f / 1024.0f);
    float rn = rsqrtf(var + 1e-6f);
    float4 us = *(const float4*)(sc + t * 4);
    float4 ub = *(const float4*)(bi + t * 4);
    ushort4 o;
    o.x = f2b(d0 * rn * us.x + ub.x);
    o.y = f2b(d1 * rn * us.y + ub.y);
    o.z = f2b(d2 * rn * us.z + ub.z);
    o.w = f2b(d3 * rn * us.w + ub.w);
    *(ushort4*)(out + (size_t)row * 1024 + t * 4) = o;
}

// ---------------------------------------------------------------------------
// GEMM: acc[M][N] = A[M][K] @ Bt[N][K]^T (bf16 in, fp32 acc).
// 128x128 tile, BK=32, DOUBLE-BUFFERED global_load_lds with ONE barrier per
// iteration: barrier -> issue prefetch into buf^1 -> compute from buf. The
// prefetch has the whole MFMA phase to land before the next barrier's
// vmcnt-drain, removing global latency from the critical path (the r8-r13
// single-buffer structures waited full latency every iter).
// op: 0: Cb=bf16(acc+bias)  1: Cb=bf16(relu(acc+bias))
//     2: Cf=acc+bias+resf   3: Cf=acc+resf      (resf may alias Cf)
// ---------------------------------------------------------------------------
__global__ __launch_bounds__(256) void gemm_bt_kernel(
    const ushort_t* __restrict__ A, const ushort_t* __restrict__ Bt,
    const float* __restrict__ bias, const float* __restrict__ resf,
    ushort_t* __restrict__ Cb, float* __restrict__ Cf,
    int M, int N, int K, int ldb, int op) {
    __shared__ __align__(16) ushort_t As[2][128 * 32];
    __shared__ __align__(16) ushort_t Bs[2][128 * 32];
    int tid = threadIdx.x;
    int m0 = blockIdx.y * 128, n0 = blockIdx.x * 128;
    int wv = tid >> 6, lane = tid & 63;
    int wr = wv & 1, wc = wv >> 1;
    int mo = wr * 64, no = wc * 64;
    int quad = lane >> 4, l16 = lane & 15;
    int k8 = quad * 8;

    floatx4 acc[4][4] = {};

    int e0 = tid * 8, e1 = 2048 + tid * 8;
    int r0 = e0 >> 5, kk0 = e0 & 31;
    int r1 = e1 >> 5, kk1 = e1 & 31;
    int wb0 = wv * 512, wb1 = 2048 + wv * 512;

    // prefetch tile 0 into buf 0
    load_lds16(A + (size_t)(m0 + r0) * K + kk0, As[0] + wb0);
    load_lds16(Bt + (size_t)(n0 + r0) * ldb + kk0, Bs[0] + wb0);
    load_lds16(A + (size_t)(m0 + r1) * K + kk1, As[0] + wb1);
    load_lds16(Bt + (size_t)(n0 + r1) * ldb + kk1, Bs[0] + wb1);

    int buf = 0;
    for (int k0 = 0; k0 < K; k0 += 32) {
        __syncthreads();   // drains prefetch (overlapped w/ prev compute)
        int nk = k0 + 32;
        if (nk < K) {
            int nb = buf ^ 1;
            load_lds16(A + (size_t)(m0 + r0) * K + nk + kk0, As[nb] + wb0);
            load_lds16(Bt + (size_t)(n0 + r0) * ldb + nk + kk0, Bs[nb] + wb0);
            load_lds16(A + (size_t)(m0 + r1) * K + nk + kk1, As[nb] + wb1);
            load_lds16(Bt + (size_t)(n0 + r1) * ldb + nk + kk1, Bs[nb] + wb1);
        }
        bf16x8 af[4], bfr[4];
#pragma unroll
        for (int i = 0; i < 4; ++i) {
            af[i]  = as_bf16x8(*(const ushort8v*)(As[buf] + (mo + i * 16 + l16) * 32 + k8));
            bfr[i] = as_bf16x8(*(const ushort8v*)(Bs[buf] + (no + i * 16 + l16) * 32 + k8));
        }
#pragma unroll
        for (int mi = 0; mi < 4; ++mi)
#pragma unroll
            for (int ni = 0; ni < 4; ++ni)
                acc[mi][ni] = __builtin_amdgcn_mfma_f32_16x16x32_bf16(
                    af[mi], bfr[ni], acc[mi][ni], 0, 0, 0);
        buf ^= 1;
    }

#pragma unroll
    for (int mi = 0; mi < 4; ++mi) {
#pragma unroll
        for (int r = 0; r < 4; ++r) {
            int row = m0 + mo + mi * 16 + quad * 4 + r;
            size_t rowoff = (size_t)row * N;
#pragma unroll
            for (int ni = 0; ni < 4; ++ni) {
                int col = n0 + no + ni * 16 + l16;
                float val = acc[mi][ni][r];
                if (op != 3) val += bias[col];
                if (op == 1) val = fmaxf(val, 0.0f);
                if (op >= 2) {
                    val += resf[rowoff + col];
                    Cf[rowoff + col] = val;
                } else {
                    Cb[rowoff + col] = f2b(val);
                }
            }
        }
    }
}

// ---------------------------------------------------------------------------
// Split-K GEMM, atomic fp32 epilogue: Cf[m][n] += acc_z (+bias if z==0).
// Same double-buffered one-barrier staging. Cf pre-init w/ residual.
// ---------------------------------------------------------------------------
__global__ __launch_bounds__(256) void gemm_bt_atomic_kernel(
    const ushort_t* __restrict__ A, const ushort_t* __restrict__ Bt,
    const float* __restrict__ bias, float* __restrict__ Cf,
    int M, int N, int lda, int ldb, int Kc) {
    __shared__ __align__(16) ushort_t As[2][128 * 32];
    __shared__ __align__(16) ushort_t Bs[2][128 * 32];
    int tid = threadIdx.x;
    int m0 = blockIdx.y * 128, n0 = blockIdx.x * 128;
    int kbase = blockIdx.z * Kc;
    int wv = tid >> 6, lane = tid & 63;
    int wr = wv & 1, wc = wv >> 1;
    int mo = wr * 64, no = wc * 64;
    int quad = lane >> 4, l16 = lane & 15;
    int k8 = quad * 8;

    floatx4 acc[4][4] = {};

    int e0 = tid * 8, e1 = 2048 + tid * 8;
    int r0 = e0 >> 5, kk0 = e0 & 31;
    int r1 = e1 >> 5, kk1 = e1 & 31;
    int wb0 = wv * 512, wb1 = 2048 + wv * 512;

    load_lds16(A + (size_t)(m0 + r0) * lda + kbase + kk0, As[0] + wb0);
    load_lds16(Bt + (size_t)(n0 + r0) * ldb + kbase + kk0, Bs[0] + wb0);
    load_lds16(A + (size_t)(m0 + r1) * lda + kbase + kk1, As[0] + wb1);
    load_lds16(Bt + (size_t)(n0 + r1) * ldb + kbase + kk1, Bs[0] + wb1);

    int buf = 0;
    for (int k0 = kbase; k0 < kbase + Kc; k0 += 32) {
        __syncthreads();
        int nk = k0 + 32;
        if (nk < kbase + Kc) {
            int nb = buf ^ 1;
            load_lds16(A + (size_t)(m0 + r0) * lda + nk + kk0, As[nb] + wb0);
            load_lds16(Bt + (size_t)(n0 + r0) * ldb + nk + kk0, Bs[nb] + wb0);
            load_lds16(A + (size_t)(m0 + r1) * lda + nk + kk1, As[nb] + wb1);
            load_lds16(Bt + (size_t)(n0 + r1) * ldb + nk + kk1, Bs[nb] + wb1);
        }
        bf16x8 af[4], bfr[4];
#pragma unroll
        for (int i = 0; i < 4; ++i) {
            af[i]  = as_bf16x8(*(const ushort8v*)(As[buf] + (mo + i * 16 + l16) * 32 + k8));
            bfr[i] = as_bf16x8(*(const ushort8v*)(Bs[buf] + (no + i * 16 + l16) * 32 + k8));
        }
#pragma unroll
        for (int mi = 0; mi < 4; ++mi)
#pragma unroll
            for (int ni = 0; ni < 4; ++ni)
                acc[mi][ni] = __builtin_amdgcn_mfma_f32_16x16x32_bf16(
                    af[mi], bfr[ni], acc[mi][ni], 0, 0, 0);
        buf ^= 1;
    }

    bool addb = (blockIdx.z == 0) && (bias != nullptr);
#pragma unroll
    for (int mi = 0; mi < 4; ++mi) {
#pragma unroll
        for (int r = 0; r < 4; ++r) {
            int row = m0 + mo + mi * 16 + quad * 4 + r;
            size_t rowoff = (size_t)row * N;
#pragma unroll
            for (int ni = 0; ni < 4; ++ni) {
                int col = n0 + no + ni * 16 + l16;
                float val = acc[mi][ni][r];
                if (addb) val += bias[col];
                unsafeAtomicAdd(&Cf[rowoff + col], val);
            }
        }
    }
}

// ---------------------------------------------------------------------------
// Flash attention. LDS-staged K/V + register prefetch; shuffle-free softmax
// (row-sum via MFMA with ones); BQ=128; S^T MFMA (A=kf,B=qf) so P packs into
// ushort4 ds_write_b64 (r13 win). P conversion via native (__bf16) casts
// (v_cvt; saves ~112 VALU ops/wave/iter vs manual f2b rounding).
// grid (S/128, B*H).
// ---------------------------------------------------------------------------
__global__ __launch_bounds__(256) void attn_kernel(
    const ushort_t* __restrict__ qkv, const ushort_t* __restrict__ vt,
    ushort_t* __restrict__ om) {
    const int LDQ = 3072, LDO = 1024;
    int bh = blockIdx.y;
    int b = bh >> 4, h = bh & 15;
    size_t qbase = (size_t)b * 2048 * LDQ + h * 64;
    size_t kbase = qbase + 1024;
    const ushort_t* vtp = vt + (size_t)bh * 64 * 2048;
    int q0 = blockIdx.x * 128;
    int tid = threadIdx.x, wv = tid >> 6, lane = tid & 63;
    int quad = lane >> 4, l16 = lane & 15;
    int k8 = quad * 8;

    __shared__ __align__(16) ushort_t Ks[64 * 72];
    __shared__ __align__(16) ushort_t Vs[64 * 72];
    __shared__ __align__(16) ushort_t Ps[4 * 32 * 76];
    ushort_t* ps = Ps + wv * 32 * 76;

    int sr0 = tid >> 3, scc0 = (tid & 7) * 8;
    int sr1 = sr0 + 32;

    bf16x8 qf[2][2];
#pragma unroll
    for (int mt = 0; mt < 2; ++mt) {
        const ushort_t* qptr = qkv + qbase + (size_t)(q0 + wv * 32 + mt * 16 + l16) * LDQ;
        qf[mt][0] = as_bf16x8(*(const ushort8v*)(qptr + k8));
        qf[mt][1] = as_bf16x8(*(const ushort8v*)(qptr + 32 + k8));
    }

    bf16x8 ones;
#pragma unroll
    for (int j = 0; j < 8; ++j) ones[j] = (__bf16)1.0f;

    floatx4 Oacc[2][4] = {};
    floatx4 lsum[2] = {};

    ushort8v kreg0, kreg1, vreg0, vreg1;
    kreg0 = *(const ushort8v*)(qkv + kbase + (size_t)sr0 * LDQ + scc0);
    kreg1 = *(const ushort8v*)(qkv + kbase + (size_t)sr1 * LDQ + scc0);
    vreg0 = *(const ushort8v*)(vtp + (size_t)sr0 * 2048 + scc0);
    vreg1 = *(const ushort8v*)(vtp + (size_t)sr1 * 2048 + scc0);

    for (int kb = 0; kb < 2048; kb += 64) {
        __syncthreads();
        *(ushort8v*)(Ks + sr0 * 72 + scc0) = kreg0;
        *(ushort8v*)(Ks + sr1 * 72 + scc0) = kreg1;
        *(ushort8v*)(Vs + sr0 * 72 + scc0) = vreg0;
        *(ushort8v*)(Vs + sr1 * 72 + scc0) = vreg1;
        __syncthreads();

        int nkb = (kb + 64 < 2048) ? kb + 64 : 0;
        kreg0 = *(const ushort8v*)(qkv + kbase + (size_t)(nkb + sr0) * LDQ + scc0);
        kreg1 = *(const ushort8v*)(qkv + kbase + (size_t)(nkb + sr1) * LDQ + scc0);
        vreg0 = *(const ushort8v*)(vtp + (size_t)sr0 * 2048 + nkb + scc0);
        vreg1 = *(const ushort8v*)(vtp + (size_t)sr1 * 2048 + nkb + scc0);

        bf16x8 kf[4][2];
#pragma unroll
        for (int kt = 0; kt < 4; ++kt)
#pragma unroll
            for (int ds = 0; ds < 2; ++ds)
                kf[kt][ds] = as_bf16x8(
                    *(const ushort8v*)(Ks + (kt * 16 + l16) * 72 + ds * 32 + k8));

        // S^T = K·Q^T: sc[mt][kt][r] = S[q=l16][k = kt*16 + quad*4 + r]
        floatx4 sc[2][4];
#pragma unroll
        for (int mt = 0; mt < 2; ++mt)
#pragma unroll
            for (int kt = 0; kt < 4; ++kt) {
                floatx4 s = {0.0f, 0.0f, 0.0f, 0.0f};
                s = __builtin_amdgcn_mfma_f32_16x16x32_bf16(kf[kt][0], qf[mt][0], s, 0, 0, 0);
                s = __builtin_amdgcn_mfma_f32_16x16x32_bf16(kf[kt][1], qf[mt][1], s, 0, 0, 0);
                sc[mt][kt] = s;
            }

        // P = exp(s/8), native bf16 cvt, packed 4-k store (ds_write_b64)
#pragma unroll
        for (int mt = 0; mt < 2; ++mt)
#pragma unroll
            for (int kt = 0; kt < 4; ++kt) {
                bf16x4 pb;
                pb[0] = (__bf16)__expf(sc[mt][kt][0] * 0.125f);
                pb[1] = (__bf16)__expf(sc[mt][kt][1] * 0.125f);
                pb[2] = (__bf16)__expf(sc[mt][kt][2] * 0.125f);
                pb[3] = (__bf16)__expf(sc[mt][kt][3] * 0.125f);
                *(bf16x4*)(ps + (mt * 16 + l16) * 76 + kt * 16 + quad * 4) = pb;
            }

        bf16x8 vf[4][2];
#pragma unroll
        for (int dt = 0; dt < 4; ++dt)
#pragma unroll
            for (int ks = 0; ks < 2; ++ks)
                vf[dt][ks] = as_bf16x8(
                    *(const ushort8v*)(Vs + (dt * 16 + l16) * 72 + ks * 32 + k8));
#pragma unroll
        for (int mt = 0; mt < 2; ++mt) {
            bf16x8 pf0 = as_bf16x8(*(const ushort8v*)(ps + (mt * 16 + l16) * 76 + k8));
            bf16x8 pf1 = as_bf16x8(*(const ushort8v*)(ps + (mt * 16 + l16) * 76 + 32 + k8));
#pragma unroll
            for (int dt = 0; dt < 4; ++dt) {
                Oacc[mt][dt] = __builtin_amdgcn_mfma_f32_16x16x32_bf16(pf0, vf[dt][0], Oacc[mt][dt], 0, 0, 0);
                Oacc[mt][dt] = __builtin_amdgcn_mfma_f32_16x16x32_bf16(pf1, vf[dt][1], Oacc[mt][dt], 0, 0, 0);
            }
            lsum[mt] = __builtin_amdgcn_mfma_f32_16x16x32_bf16(pf0, ones, lsum[mt], 0, 0, 0);
            lsum[mt] = __builtin_amdgcn_mfma_f32_16x16x32_bf16(pf1, ones, lsum[mt], 0, 0, 0);
        }
    }

#pragma unroll
    for (int mt = 0; mt < 2; ++mt)
#pragma unroll
        for (int r = 0; r < 4; ++r) {
            float inv = 1.0f / lsum[mt][r];
            size_t rowoff = (size_t)(b * 2048 + q0 + wv * 32 + mt * 16 + quad * 4 + r) * LDO + h * 64;
#pragma unroll
            for (int dt = 0; dt < 4; ++dt)
                om[rowoff + dt * 16 + l16] = f2b(Oacc[mt][dt][r] * inv);
        }
}

// ---------------------------------------------------------------------------
// Workspace map (bf16 elems, M1 = 1048576), peak 28M elems = 56 MB (proven):
//   qkvT [0,3M)  WoT [3M,4M)  W1T [4M,8M)  W2T [8M,12M)
//   h/attnout [12M,16M)   qkv [16M,28M)
//   h2 -> [0,4M) after qkvT/WoT die; ffbuf -> [12M,28M) after attnout/qkv die
// d_out timeline: bqkv (12 KB) -> vt (8 MB bf16) -> outf (x2 fp32 16 MB).
// ---------------------------------------------------------------------------
extern "C" void kernel_launch(void* const* d_in, const int* in_sizes, int n_in,
                              void* d_out, int out_size, void* d_ws, size_t ws_size,
                              hipStream_t stream) {
    const float* x    = (const float*)d_in[0];
    const float* Wq   = (const float*)d_in[1];
    const float* bq   = (const float*)d_in[2];
    const float* Wk   = (const float*)d_in[3];
    const float* bk   = (const float*)d_in[4];
    const float* Wv   = (const float*)d_in[5];
    const float* bv   = (const float*)d_in[6];
    const float* Wo   = (const float*)d_in[7];
    const float* bo   = (const float*)d_in[8];
    const float* W1   = (const float*)d_in[9];
    const float* b1   = (const float*)d_in[10];
    const float* W2   = (const float*)d_in[11];
    const float* b2   = (const float*)d_in[12];
    const float* ln1s = (const float*)d_in[13];
    const float* ln1b = (const float*)d_in[14];
    const float* ln2s = (const float*)d_in[15];
    const float* ln2b = (const float*)d_in[16];
    float*    outf = (float*)d_out;
    ushort_t* ws   = (ushort_t*)d_ws;

    const size_t M1 = 1048576;
    ushort_t* qkvT    = ws;
    ushort_t* WoT     = ws + 3 * M1;
    ushort_t* W1T     = ws + 4 * M1;
    ushort_t* W2T     = ws + 8 * M1;
    ushort_t* h       = ws + 12 * M1;
    ushort_t* attnout = ws + 12 * M1;
    ushort_t* qkv     = ws + 16 * M1;
    ushort_t* h2      = ws;
    ushort_t* ffbuf   = ws + 12 * M1;
    float*    bqkv    = (float*)d_out;
    ushort_t* vtbuf   = (ushort_t*)d_out;

    dim3 tb(32, 8);

    concat3_kernel<<<12, 256, 0, stream>>>(bq, bk, bv, bqkv);
    transpose_all_kernel<<<12288, tb, 0, stream>>>(
        Wq, Wk, Wv, Wo, W1, W2,
        qkvT, qkvT + M1, qkvT + 2 * M1, WoT, W1T, W2T);

    // h = LN1(x)
    ln_f32_kernel<<<4096, 256, 0, stream>>>(x, ln1s, ln1b, h);

    // qkv = h @ [Wq|Wk|Wv] + bqkv  (N=3072, 768 blocks)
    gemm_bt_kernel<<<dim3(24, 32), 256, 0, stream>>>(
        h, qkvT, bqkv, nullptr, qkv, nullptr, 4096, 3072, 1024, 1024, 0);

    // vt (per-head V^T) -> d_out (bqkv dead)
    transpose_v_kernel<<<dim3(64, 2, 32), tb, 0, stream>>>(qkv, vtbuf);

    // attention -> attnout; BQ=128, grid 512 blocks
    attn_kernel<<<dim3(16, 32), 256, 0, stream>>>(qkv, vtbuf, attnout);

    // outf = x (vt dead), then x2 = outf += attnout@Wo + bo (split-K 4)
    copy_f32_kernel<<<4096, 256, 0, stream>>>(x, outf);
    gemm_bt_atomic_kernel<<<dim3(8, 32, 4), 256, 0, stream>>>(
        attnout, WoT, bo, outf, 4096, 1024, 1024, 1024, 256);

    // h2 = LN2(x2)
    ln_f32_kernel<<<4096, 256, 0, stream>>>(outf, ln2s, ln2b, h2);

    // ffbuf = relu(h2 @ W1 + b1)  (N=4096, 1024 blocks)
    gemm_bt_kernel<<<dim3(32, 32), 256, 0, stream>>>(
        h2, W1T, b1, nullptr, ffbuf, nullptr, 4096, 4096, 1024, 1024, 1);

    // out = x2 += ffbuf @ W2 + b2  (split-K 4, 1024 blocks, atomic fp32)
    gemm_bt_atomic_kernel<<<dim3(8, 32, 4), 256, 0, stream>>>(
        ffbuf, W2T, b2, outf, 4096, 1024, 4096, 4096, 1024);
}